// Round 11
// baseline (583.628 us; speedup 1.0000x reference)
//
#include <hip/hip_runtime.h>

// GCN: 2x (GCNConv + ReLU) + FC.  N=100000, E=1600000, F: 128 -> 64 -> 64 -> 32. fp32.
//
// R11: mm lane-map swap. R9/R10's rg=t/16 made 16 lanes read IDENTICAL X
// addresses -> 64 B unique per load instr -> ~0.5 KB in flight/wave -> latency-
// bound at 28% VALU (both LDS-staged R8 and streamed R9 plateaued ~50 us).
// Now rg = t%RG (16 distinct rows per load instr ~ 1 KB lines in flight),
// cg = t/RG (W reads become 4-addr LDS broadcast, free), 8 rows/thread
// (TILE_R=128; W-LDS instrs per fma halved), odd/even A/B buffers (no copies).
// agg: scalar srt + pair-gather (R10); Hs bf16 (R7); partition (R6) unchanged.

#define THREADS 256
#define EPB 4096          // edges per block in hist/bin passes
#define BKT 256           // nodes per bucket (dlocal = dst & 255)
#define SORT_CAP 8192     // max edges per bucket in LDS (mean 4092, sigma ~64)

typedef unsigned short ushort_t;

__device__ __forceinline__ ushort_t f2bf(float f) {  // round-to-nearest-even
    unsigned u = __float_as_uint(f);
    u += 0x7FFFu + ((u >> 16) & 1u);
    return (ushort_t)(u >> 16);
}
__device__ __forceinline__ float bflo(unsigned v) { return __uint_as_float(v << 16); }
__device__ __forceinline__ float bfhi(unsigned v) { return __uint_as_float(v & 0xFFFF0000u); }

// ---- Pass 1: per-(block,bucket) histogram ---------------------------------

__global__ __launch_bounds__(THREADS) void histB_kernel(const int* __restrict__ dst, int E,
                                                        int nb, int nblk,
                                                        int* __restrict__ bh) {
    __shared__ int h[512];
    for (int i = threadIdx.x; i < nb; i += THREADS) h[i] = 0;
    __syncthreads();
    const int e0 = blockIdx.x * EPB;
    const int e1 = min(e0 + EPB, E);
    for (int e = e0 + threadIdx.x; e < e1; e += THREADS)
        atomicAdd(&h[dst[e] >> 8], 1);
    __syncthreads();
    for (int i = threadIdx.x; i < nb; i += THREADS)
        bh[(size_t)i * nblk + blockIdx.x] = h[i];   // [bucket][block]
}

// ---- Pass 2a: per-bucket row scan (block b owns row b) --------------------

__global__ __launch_bounds__(THREADS) void scanS_kernel(int* __restrict__ bh,
                                                        int nb, int nblk,
                                                        int* __restrict__ btot) {
    __shared__ int s[THREADS];
    const int b = blockIdx.x, t = threadIdx.x;
    int* rowp = bh + (size_t)b * nblk;
    const int run = (nblk + THREADS - 1) / THREADS;
    const int lo = min(t * run, nblk), hi = min(lo + run, nblk);
    int v[4];
    int sum = 0;
    for (int i = lo; i < hi; ++i) { v[i - lo] = rowp[i]; sum += v[i - lo]; }
    s[t] = sum;
    __syncthreads();
    for (int off = 1; off < THREADS; off <<= 1) {
        int u = (t >= off) ? s[t - off] : 0;
        __syncthreads();
        s[t] += u;
        __syncthreads();
    }
    int pre = s[t] - sum;
    for (int i = lo; i < hi; ++i) { rowp[i] = pre; pre += v[i - lo]; }
    if (t == THREADS - 1) btot[b] = s[t];
}

// ---- Pass 2b: scan bucket totals -> bstart[0..nb], bstart[nb]=E -----------

__global__ __launch_bounds__(512) void scanT_kernel(const int* __restrict__ btot,
                                                    int nb, int E,
                                                    int* __restrict__ bstart) {
    __shared__ int s[512];
    const int t = threadIdx.x;
    const int v = (t < nb) ? btot[t] : 0;
    s[t] = v;
    __syncthreads();
    for (int off = 1; off < 512; off <<= 1) {
        int u = (t >= off) ? s[t - off] : 0;
        __syncthreads();
        s[t] += u;
        __syncthreads();
    }
    if (t < nb) bstart[t] = s[t] - v;
    if (t == 0) bstart[nb] = E;
}

// ---- Pass 3: scatter edges into bucket-contiguous staging -----------------

__global__ __launch_bounds__(THREADS) void binB_kernel(const int* __restrict__ src,
                                                       const int* __restrict__ dst, int E,
                                                       int nb, int nblk,
                                                       const int* __restrict__ bh,
                                                       const int* __restrict__ bstart,
                                                       unsigned* __restrict__ stage) {
    __shared__ int cur[512];
    for (int i = threadIdx.x; i < nb; i += THREADS)
        cur[i] = bstart[i] + bh[(size_t)i * nblk + blockIdx.x];
    __syncthreads();
    const int e0 = blockIdx.x * EPB;
    const int e1 = min(e0 + EPB, E);
    for (int e = e0 + threadIdx.x; e < e1; e += THREADS) {
        const int d = dst[e];
        const int pos = atomicAdd(&cur[d >> 8], 1);
        stage[pos] = ((unsigned)(d & (BKT - 1)) << 17) | (unsigned)src[e];
    }
}

// ---- Pass 4: per-bucket in-LDS counting sort (in place) + row/dinv --------

__global__ __launch_bounds__(THREADS) void sortB_kernel(unsigned* __restrict__ stage,
                                                        const int* __restrict__ bstart,
                                                        int nb, int N,
                                                        int* __restrict__ row,
                                                        float* __restrict__ dinv) {
    __shared__ unsigned buf[SORT_CAP];
    __shared__ int cnt[BKT], cur[BKT], scn[BKT];
    const int b = blockIdx.x, t = threadIdx.x;
    const int bs = bstart[b];
    const int be = bstart[b + 1];
    const int m = be - bs;
    cnt[t] = 0;
    __syncthreads();
    for (int i = t; i < m; i += THREADS) {
        const unsigned v = stage[bs + i];
        buf[i] = v;
        atomicAdd(&cnt[v >> 17], 1);
    }
    __syncthreads();
    const int c = cnt[t];
    scn[t] = c;
    __syncthreads();
    for (int off = 1; off < BKT; off <<= 1) {
        int u = (t >= off) ? scn[t - off] : 0;
        __syncthreads();
        scn[t] += u;
        __syncthreads();
    }
    const int excl = scn[t] - c;
    cur[t] = excl;
    const int node = b * BKT + t;
    if (node < N) {
        row[node] = bs + excl;
        dinv[node] = rsqrtf((float)c + 1.0f);  // +1 self-loop
    }
    __syncthreads();
    for (int i = t; i < m; i += THREADS) {
        const unsigned v = buf[i];
        const int pos = atomicAdd(&cur[v >> 17], 1);
        stage[bs + pos] = v & 0x1FFFFu;        // strip dlocal: plain src
    }
}

// ---- Dense matmul: Y[N,M] = (X[N,K] @ W[K,M]) [*dinv[row]] [+bias] ---------
// W-only LDS. rg = t%RG: one X load instr touches RG distinct rows (RG cache
// lines in flight); cg = t/RG: W LDS reads are few-address broadcasts.
// R rows/thread; odd/even A/B chunk buffers (compute A, reload A, compute B,
// reload B) -> no register copies, ~2-chunk load lead. OOB rows: pointer
// clamped to N-1, store guard discards.

template <int K, int M, int R, bool BIAS, bool SCALE, bool OUT_BF16, typename OutT>
__global__ __launch_bounds__(THREADS) void mm_kernel(const float* __restrict__ X,
                                                     const float* __restrict__ W,
                                                     const float* __restrict__ bias,
                                                     const float* __restrict__ dinv,
                                                     OutT* __restrict__ Y, int N) {
    constexpr int CG = M / 4;            // col groups (4 cols each)
    constexpr int RG = THREADS / CG;     // row groups
    constexpr int TILE_R = RG * R;
    __shared__ float Ws[K * M];
    const int t = threadIdx.x;
    for (int i = t; i < K * M / 4; i += THREADS)
        ((float4*)Ws)[i] = ((const float4*)W)[i];
    __syncthreads();

    const int rg = t % RG;               // lane-distinct rows within a wave
    const int cg = t / RG;               // broadcast W address within a wave
    const int row0 = blockIdx.x * TILE_R;
    const int r0 = row0 + rg * R;
    const float* xp[R];
#pragma unroll
    for (int i = 0; i < R; ++i) xp[i] = X + (size_t)min(r0 + i, N - 1) * K;
    const float* wb = &Ws[cg * 4];
    float acc[R][4] = {};

    auto chunk = [&](const float4* Xb, int kk) {
        const float4 wv0 = *(const float4*)(wb + (size_t)(kk + 0) * M);
        const float4 wv1 = *(const float4*)(wb + (size_t)(kk + 1) * M);
        const float4 wv2 = *(const float4*)(wb + (size_t)(kk + 2) * M);
        const float4 wv3 = *(const float4*)(wb + (size_t)(kk + 3) * M);
#pragma unroll
        for (int i = 0; i < R; ++i) {
            acc[i][0] = fmaf(Xb[i].x, wv0.x, acc[i][0]);
            acc[i][1] = fmaf(Xb[i].x, wv0.y, acc[i][1]);
            acc[i][2] = fmaf(Xb[i].x, wv0.z, acc[i][2]);
            acc[i][3] = fmaf(Xb[i].x, wv0.w, acc[i][3]);
            acc[i][0] = fmaf(Xb[i].y, wv1.x, acc[i][0]);
            acc[i][1] = fmaf(Xb[i].y, wv1.y, acc[i][1]);
            acc[i][2] = fmaf(Xb[i].y, wv1.z, acc[i][2]);
            acc[i][3] = fmaf(Xb[i].y, wv1.w, acc[i][3]);
            acc[i][0] = fmaf(Xb[i].z, wv2.x, acc[i][0]);
            acc[i][1] = fmaf(Xb[i].z, wv2.y, acc[i][1]);
            acc[i][2] = fmaf(Xb[i].z, wv2.z, acc[i][2]);
            acc[i][3] = fmaf(Xb[i].z, wv2.w, acc[i][3]);
            acc[i][0] = fmaf(Xb[i].w, wv3.x, acc[i][0]);
            acc[i][1] = fmaf(Xb[i].w, wv3.y, acc[i][1]);
            acc[i][2] = fmaf(Xb[i].w, wv3.z, acc[i][2]);
            acc[i][3] = fmaf(Xb[i].w, wv3.w, acc[i][3]);
        }
    };

    float4 A[R], B[R];
#pragma unroll
    for (int i = 0; i < R; ++i) A[i] = *(const float4*)(xp[i] + 0);
#pragma unroll
    for (int i = 0; i < R; ++i) B[i] = *(const float4*)(xp[i] + 4);

#pragma unroll 2
    for (int k = 0; k < K; k += 8) {
        chunk(A, k);
        const int ka = min(k + 8, K - 4);
#pragma unroll
        for (int i = 0; i < R; ++i) A[i] = *(const float4*)(xp[i] + ka);
        chunk(B, k + 4);
        const int kb = min(k + 12, K - 4);
#pragma unroll
        for (int i = 0; i < R; ++i) B[i] = *(const float4*)(xp[i] + kb);
    }

#pragma unroll
    for (int i = 0; i < R; ++i) {
        const int r = r0 + i;
        if (r < N) {
            float4 o = {acc[i][0], acc[i][1], acc[i][2], acc[i][3]};
            if (SCALE) {
                const float d = dinv[r];
                o.x *= d; o.y *= d; o.z *= d; o.w *= d;
            }
            if (BIAS) {
                o.x += bias[cg * 4 + 0]; o.y += bias[cg * 4 + 1];
                o.z += bias[cg * 4 + 2]; o.w += bias[cg * 4 + 3];
            }
            if (OUT_BF16) {
                ushort4 p = {f2bf(o.x), f2bf(o.y), f2bf(o.z), f2bf(o.w)};
                *(ushort4*)((ushort_t*)Y + (size_t)r * M + cg * 4) = p;
            } else {
                *(float4*)((float*)Y + (size_t)r * M + cg * 4) = o;
            }
        }
    }
}

// ---- Aggregation: wave per node; lane owns a feature PAIR (ushort2 dword).
// 16-edge chunks: srt read through a wave-uniform pointer (scalar/broadcast
// loads); half 0 takes edges 0-7, half 1 takes 8-15; 8 gathers in flight.
// Tail: same read (past-end stays inside ws), clamped indices, masked adds.

__global__ __launch_bounds__(THREADS) void agg_kernel(const unsigned* __restrict__ srt,
                                                      const int* __restrict__ row,
                                                      const float* __restrict__ dinv,
                                                      const unsigned* __restrict__ H2,  // [N][32] dwords (bf16 pairs)
                                                      const float* __restrict__ bias,
                                                      float* __restrict__ out, int N, int E) {
    const int idx = blockIdx.x * blockDim.x + threadIdx.x;
    const int node = idx >> 6;
    if (node >= N) return;
    const int l = threadIdx.x & 63;
    const int half = l >> 5;          // 0: edges 0-7 of chunk, 1: edges 8-15
    const int f2 = l & 31;            // feature pair (2*f2, 2*f2+1)
    const int start = row[node];
    const int end = (node + 1 < N) ? row[node + 1] : E;
    float acc0 = 0.0f, acc1 = 0.0f;

    int base = start;
    for (; base + 16 <= end; base += 16) {
        const unsigned* sp = srt + __builtin_amdgcn_readfirstlane(base);
        const unsigned g0 = sp[0],  g1 = sp[1],  g2 = sp[2],  g3 = sp[3];
        const unsigned g4 = sp[4],  g5 = sp[5],  g6 = sp[6],  g7 = sp[7];
        const unsigned h0 = sp[8],  h1 = sp[9],  h2 = sp[10], h3 = sp[11];
        const unsigned h4 = sp[12], h5 = sp[13], h6 = sp[14], h7 = sp[15];
        const unsigned e0 = half ? h0 : g0, e1 = half ? h1 : g1;
        const unsigned e2 = half ? h2 : g2, e3 = half ? h3 : g3;
        const unsigned e4 = half ? h4 : g4, e5 = half ? h5 : g5;
        const unsigned e6 = half ? h6 : g6, e7 = half ? h7 : g7;
        const unsigned v0 = H2[(size_t)e0 * 32 + f2];
        const unsigned v1 = H2[(size_t)e1 * 32 + f2];
        const unsigned v2 = H2[(size_t)e2 * 32 + f2];
        const unsigned v3 = H2[(size_t)e3 * 32 + f2];
        const unsigned v4 = H2[(size_t)e4 * 32 + f2];
        const unsigned v5 = H2[(size_t)e5 * 32 + f2];
        const unsigned v6 = H2[(size_t)e6 * 32 + f2];
        const unsigned v7 = H2[(size_t)e7 * 32 + f2];
        acc0 += bflo(v0); acc1 += bfhi(v0);
        acc0 += bflo(v1); acc1 += bfhi(v1);
        acc0 += bflo(v2); acc1 += bfhi(v2);
        acc0 += bflo(v3); acc1 += bfhi(v3);
        acc0 += bflo(v4); acc1 += bfhi(v4);
        acc0 += bflo(v5); acc1 += bfhi(v5);
        acc0 += bflo(v6); acc1 += bfhi(v6);
        acc0 += bflo(v7); acc1 += bfhi(v7);
    }
    if (base < end) {
        const unsigned* sp = srt + __builtin_amdgcn_readfirstlane(base);
        const unsigned cap = (unsigned)(N - 1);
        const int j0 = base + half * 8;
#pragma unroll
        for (int k = 0; k < 8; ++k) {
            const unsigned raw = half ? sp[8 + k] : sp[k];   // may be past end: in-ws garbage
            const bool ok = (j0 + k) < end;
            const unsigned s = min(raw & 0x1FFFFu, cap);     // clamp to valid H2 row
            const unsigned v = H2[(size_t)s * 32 + f2];
            acc0 += ok ? bflo(v) : 0.0f;
            acc1 += ok ? bfhi(v) : 0.0f;
        }
    }

    acc0 += __shfl_xor(acc0, 32, 64);
    acc1 += __shfl_xor(acc1, 32, 64);
    if (half == 0) {
        const unsigned sv = H2[(size_t)node * 32 + f2];   // self-loop row
        const float d = dinv[node];
        const float2 b = *(const float2*)(bias + f2 * 2);
        const float o0 = fmaxf(fmaf(acc0 + bflo(sv), d, b.x), 0.0f);
        const float o1 = fmaxf(fmaf(acc1 + bfhi(sv), d, b.y), 0.0f);
        float2 o = {o0, o1};
        *(float2*)(out + (size_t)node * 64 + f2 * 2) = o;
    }
}

// ---- Launch ----------------------------------------------------------------

extern "C" void kernel_launch(void* const* d_in, const int* in_sizes, int n_in,
                              void* d_out, int out_size, void* d_ws, size_t ws_size,
                              hipStream_t stream) {
    const float* x   = (const float*)d_in[0];
    const int*   ei  = (const int*)d_in[1];   // [2, E] int32
    const float* W1  = (const float*)d_in[3];
    const float* b1  = (const float*)d_in[4];
    const float* W2  = (const float*)d_in[5];
    const float* b2  = (const float*)d_in[6];
    const float* Wfc = (const float*)d_in[7];
    const float* bfc = (const float*)d_in[8];
    float* out = (float*)d_out;

    const int N = in_sizes[0] / 128;
    const int E = in_sizes[1] / 2;
    const int* src = ei;
    const int* dst = ei + E;

    const int nb   = (N + BKT - 1) / BKT;     // 391 buckets
    const int nblk = (E + EPB - 1) / EPB;     // 391 edge-chunks

    // ws: bh[nb*nblk] | btot[nb] | bstart[nb+1] | stage[E] | row[N] | dinv[N]
    //     | bufF[N*64] fp32 | bufH[N*64] bf16   (~46 MB)
    int*      bh     = (int*)d_ws;
    int*      btot   = bh + (size_t)nb * nblk;
    int*      bstart = btot + nb;
    unsigned* stage  = (unsigned*)(bstart + nb + 1);
    int*      row    = (int*)(stage + E);
    float*    dinv   = (float*)(row + N);
    float*    bufF   = dinv + N;                             // fp32 [N,64]
    ushort_t* bufH   = (ushort_t*)(bufF + (size_t)N * 64);   // bf16 [N,64]

    const int gW = ((N * 64) + THREADS - 1) / THREADS;  // one wave per node

    // Partition -> sorted CSR (shared by both conv layers).
    histB_kernel<<<nblk, THREADS, 0, stream>>>(dst, E, nb, nblk, bh);
    scanS_kernel<<<nb, THREADS, 0, stream>>>(bh, nb, nblk, btot);
    scanT_kernel<<<1, 512, 0, stream>>>(btot, nb, E, bstart);
    binB_kernel<<<nblk, THREADS, 0, stream>>>(src, dst, E, nb, nblk, bh, bstart, stage);
    sortB_kernel<<<nb, THREADS, 0, stream>>>(stage, bstart, nb, N, row, dinv);

    // Layer 1: Hs1 = bf16((x @ W1)*dinv); relu1 = relu(dinv*(Hs1 self+gather)+b1) fp32
    mm_kernel<128, 64, 8, false, true, true><<<(N + 127) / 128, THREADS, 0, stream>>>(
        x, W1, nullptr, dinv, bufH, N);
    agg_kernel<<<gW, THREADS, 0, stream>>>(stage, row, dinv, (const unsigned*)bufH, b1, bufF, N, E);

    // Layer 2
    mm_kernel<64, 64, 8, false, true, true><<<(N + 127) / 128, THREADS, 0, stream>>>(
        bufF, W2, nullptr, dinv, bufH, N);
    agg_kernel<<<gW, THREADS, 0, stream>>>(stage, row, dinv, (const unsigned*)bufH, b2, bufF, N, E);

    // FC: out = relu2 @ Wfc + bfc (fp32 in/out)  (R=4 -> TILE_R = 32*4 = 128)
    mm_kernel<64, 32, 4, true, false, false><<<(N + 127) / 128, THREADS, 0, stream>>>(
        bufF, Wfc, bfc, nullptr, out, N);
}

// Round 12
// 298.850 us; speedup vs baseline: 1.9529x; 1.9529x over previous
//
#include <hip/hip_runtime.h>

// GCN: 2x (GCNConv + ReLU) + FC.  N=100000, E=1600000, F: 128 -> 64 -> 64 -> 32. fp32.
//
// R12: pipeline fusion on the R10 structure (R11's mm lane-map swap regressed 4x
// — reverted; R10 mm = best known ~50 us).
//  - histB fused into mm1 (independent work; hist blocks 0..nblk-1, mm blocks after).
//    mm1 therefore writes UNSCALED bf16 H (dinv not yet known).
//  - sortB additionally rescales its bucket's 256 H rows by dinv in place
//    (coalesced; one extra bf16 rounding on Hs1 only).
//  - scanT folded into binB (each block re-scans the 391 bucket totals in LDS;
//    block 0 publishes bstart[] for sortB).
//  8 dispatches total (was 10). agg (R10 pair-gather + scalar srt), mm (R10
//  broadcast-load depth-2 prefetch) unchanged.

#define THREADS 256
#define BIN_T 512         // binB block size (inline 512-slot scan)
#define EPB 4096          // edges per block in hist/bin passes
#define BKT 256           // nodes per bucket (dlocal = dst & 255)
#define SORT_CAP 8192     // max edges per bucket in LDS (mean 4092, sigma ~64)

typedef unsigned short ushort_t;

__device__ __forceinline__ ushort_t f2bf(float f) {  // round-to-nearest-even
    unsigned u = __float_as_uint(f);
    u += 0x7FFFu + ((u >> 16) & 1u);
    return (ushort_t)(u >> 16);
}
__device__ __forceinline__ float bflo(unsigned v) { return __uint_as_float(v << 16); }
__device__ __forceinline__ float bfhi(unsigned v) { return __uint_as_float(v & 0xFFFF0000u); }

// ---- Fused kernel 1: histogram blocks + mm1 blocks -------------------------
// Blocks [0, nblk): per-(block,bucket) histogram of dst>>8 into bh[bucket][block].
// Blocks [nblk, ...): Y = X @ W (no scale), bf16 out.  W-only LDS, X streamed
// global->reg with depth-2 prefetch (R10 layout: rg=t/CG, broadcast X loads).

template <int K, int M, int TILE_R>
__global__ __launch_bounds__(THREADS) void mmh_kernel(const float* __restrict__ X,
                                                      const float* __restrict__ W,
                                                      ushort_t* __restrict__ Y, int N,
                                                      const int* __restrict__ dst, int E,
                                                      int nb, int nblk,
                                                      int* __restrict__ bh) {
    static_assert((TILE_R / 4) * (M / 4) == THREADS, "tile/thread mismatch");
    __shared__ float Ws[K * M];          // mm path; hist path aliases first 2 KB
    const int t = threadIdx.x;

    if ((int)blockIdx.x < (unsigned)nblk) {
        // ---------------- histogram path ----------------
        int* h = (int*)Ws;
        for (int i = t; i < nb; i += THREADS) h[i] = 0;
        __syncthreads();
        const int e0 = blockIdx.x * EPB;
        const int e1 = min(e0 + EPB, E);
        for (int e = e0 + t; e < e1; e += THREADS)
            atomicAdd(&h[dst[e] >> 8], 1);
        __syncthreads();
        for (int i = t; i < nb; i += THREADS)
            bh[(size_t)i * nblk + blockIdx.x] = h[i];
        return;
    }

    // ---------------- mm path (R10) ----------------
    const int bid = blockIdx.x - nblk;
    for (int i = t; i < K * M / 4; i += THREADS)
        ((float4*)Ws)[i] = ((const float4*)W)[i];
    __syncthreads();

    constexpr int CG = M / 4;
    const int rg = t / CG;
    const int cg = t % CG;
    const int r0 = bid * TILE_R + rg * 4;
    const float* xp0 = X + (size_t)min(r0 + 0, N - 1) * K;
    const float* xp1 = X + (size_t)min(r0 + 1, N - 1) * K;
    const float* xp2 = X + (size_t)min(r0 + 2, N - 1) * K;
    const float* xp3 = X + (size_t)min(r0 + 3, N - 1) * K;
    const float* wb = &Ws[cg * 4];
    float acc[4][4] = {};

#define GCN_STEP(XV, WV)                                                                  \
    acc[0][0] = fmaf(xv0.XV, WV.x, acc[0][0]); acc[0][1] = fmaf(xv0.XV, WV.y, acc[0][1]); \
    acc[0][2] = fmaf(xv0.XV, WV.z, acc[0][2]); acc[0][3] = fmaf(xv0.XV, WV.w, acc[0][3]); \
    acc[1][0] = fmaf(xv1.XV, WV.x, acc[1][0]); acc[1][1] = fmaf(xv1.XV, WV.y, acc[1][1]); \
    acc[1][2] = fmaf(xv1.XV, WV.z, acc[1][2]); acc[1][3] = fmaf(xv1.XV, WV.w, acc[1][3]); \
    acc[2][0] = fmaf(xv2.XV, WV.x, acc[2][0]); acc[2][1] = fmaf(xv2.XV, WV.y, acc[2][1]); \
    acc[2][2] = fmaf(xv2.XV, WV.z, acc[2][2]); acc[2][3] = fmaf(xv2.XV, WV.w, acc[2][3]); \
    acc[3][0] = fmaf(xv3.XV, WV.x, acc[3][0]); acc[3][1] = fmaf(xv3.XV, WV.y, acc[3][1]); \
    acc[3][2] = fmaf(xv3.XV, WV.z, acc[3][2]); acc[3][3] = fmaf(xv3.XV, WV.w, acc[3][3]);

#define GCN_CHUNK(KK)                                                   \
    {                                                                   \
        const float4 wv0 = *(const float4*)(wb + (size_t)(KK + 0) * M); \
        const float4 wv1 = *(const float4*)(wb + (size_t)(KK + 1) * M); \
        const float4 wv2 = *(const float4*)(wb + (size_t)(KK + 2) * M); \
        const float4 wv3 = *(const float4*)(wb + (size_t)(KK + 3) * M); \
        GCN_STEP(x, wv0)                                                \
        GCN_STEP(y, wv1)                                                \
        GCN_STEP(z, wv2)                                                \
        GCN_STEP(w, wv3)                                                \
    }

    float4 A0 = *(const float4*)(xp0 + 0), A1 = *(const float4*)(xp1 + 0);
    float4 A2 = *(const float4*)(xp2 + 0), A3 = *(const float4*)(xp3 + 0);
    float4 B0 = *(const float4*)(xp0 + 4), B1 = *(const float4*)(xp1 + 4);
    float4 B2 = *(const float4*)(xp2 + 4), B3 = *(const float4*)(xp3 + 4);
#pragma unroll 4
    for (int k = 0; k < K; k += 4) {
        const float4 xv0 = A0, xv1 = A1, xv2 = A2, xv3 = A3;
        A0 = B0; A1 = B1; A2 = B2; A3 = B3;
        const int kn = min(k + 8, K - 4);
        B0 = *(const float4*)(xp0 + kn);
        B1 = *(const float4*)(xp1 + kn);
        B2 = *(const float4*)(xp2 + kn);
        B3 = *(const float4*)(xp3 + kn);
        GCN_CHUNK(k)
    }
#undef GCN_CHUNK
#undef GCN_STEP

#pragma unroll
    for (int i = 0; i < 4; ++i) {
        const int r = r0 + i;
        if (r < N) {
            ushort4 p = {f2bf(acc[i][0]), f2bf(acc[i][1]), f2bf(acc[i][2]), f2bf(acc[i][3])};
            *(ushort4*)(Y + (size_t)r * M + cg * 4) = p;
        }
    }
}

// ---- Pass 2: per-bucket row scan (block b owns row b) ----------------------

__global__ __launch_bounds__(THREADS) void scanS_kernel(int* __restrict__ bh,
                                                        int nb, int nblk,
                                                        int* __restrict__ btot) {
    __shared__ int s[THREADS];
    const int b = blockIdx.x, t = threadIdx.x;
    int* rowp = bh + (size_t)b * nblk;
    const int run = (nblk + THREADS - 1) / THREADS;
    const int lo = min(t * run, nblk), hi = min(lo + run, nblk);
    int v[4];
    int sum = 0;
    for (int i = lo; i < hi; ++i) { v[i - lo] = rowp[i]; sum += v[i - lo]; }
    s[t] = sum;
    __syncthreads();
    for (int off = 1; off < THREADS; off <<= 1) {
        int u = (t >= off) ? s[t - off] : 0;
        __syncthreads();
        s[t] += u;
        __syncthreads();
    }
    int pre = s[t] - sum;
    for (int i = lo; i < hi; ++i) { rowp[i] = pre; pre += v[i - lo]; }
    if (t == THREADS - 1) btot[b] = s[t];
}

// ---- Pass 3: bin edges; inline scan of bucket totals (scanT folded in) -----
// Each block scans btot[0..nb) in LDS (512 slots); cur[i] = bucketbase + row-
// relative offset.  Block 0 publishes bstart[0..nb] (+bstart[nb]=E) for sortB.

__global__ __launch_bounds__(BIN_T) void binB_kernel(const int* __restrict__ src,
                                                     const int* __restrict__ dst, int E,
                                                     int nb, int nblk,
                                                     const int* __restrict__ bh,
                                                     const int* __restrict__ btot,
                                                     int* __restrict__ bstart,
                                                     unsigned* __restrict__ stage) {
    __shared__ int s[BIN_T];
    __shared__ int cur[BIN_T];
    const int t = threadIdx.x;
    const int v = (t < nb) ? btot[t] : 0;
    s[t] = v;
    __syncthreads();
    for (int off = 1; off < BIN_T; off <<= 1) {
        int u = (t >= off) ? s[t - off] : 0;
        __syncthreads();
        s[t] += u;
        __syncthreads();
    }
    const int base = s[t] - v;   // exclusive bucket base
    if (t < nb) cur[t] = base + bh[(size_t)t * nblk + blockIdx.x];
    if (blockIdx.x == 0) {
        if (t < nb) bstart[t] = base;
        if (t == 0) bstart[nb] = E;
    }
    __syncthreads();
    const int e0 = blockIdx.x * EPB;
    const int e1 = min(e0 + EPB, E);
    for (int e = e0 + t; e < e1; e += BIN_T) {
        const int d = dst[e];
        const int pos = atomicAdd(&cur[d >> 8], 1);
        stage[pos] = ((unsigned)(d & (BKT - 1)) << 17) | (unsigned)src[e];
    }
}

// ---- Pass 4: per-bucket in-LDS counting sort + row/dinv + H rescale --------
// After sorting, the block rescales its bucket's 256 bf16 H rows by dinv
// (layer-1 scaling deferred from the fused mm1).

__global__ __launch_bounds__(THREADS) void sortB_kernel(unsigned* __restrict__ stage,
                                                        const int* __restrict__ bstart,
                                                        int nb, int N,
                                                        int* __restrict__ row,
                                                        float* __restrict__ dinv,
                                                        unsigned* __restrict__ H2) {
    __shared__ unsigned buf[SORT_CAP];
    __shared__ int cnt[BKT], cur[BKT], scn[BKT];
    __shared__ float dv[BKT];
    const int b = blockIdx.x, t = threadIdx.x;
    const int bs = bstart[b];
    const int be = bstart[b + 1];
    const int m = be - bs;
    cnt[t] = 0;
    __syncthreads();
    for (int i = t; i < m; i += THREADS) {
        const unsigned v = stage[bs + i];
        buf[i] = v;
        atomicAdd(&cnt[v >> 17], 1);
    }
    __syncthreads();
    const int c = cnt[t];
    scn[t] = c;
    __syncthreads();
    for (int off = 1; off < BKT; off <<= 1) {
        int u = (t >= off) ? scn[t - off] : 0;
        __syncthreads();
        scn[t] += u;
        __syncthreads();
    }
    const int excl = scn[t] - c;
    cur[t] = excl;
    const float d = rsqrtf((float)c + 1.0f);  // +1 self-loop
    dv[t] = d;
    const int node = b * BKT + t;
    if (node < N) {
        row[node] = bs + excl;
        dinv[node] = d;
    }
    __syncthreads();
    for (int i = t; i < m; i += THREADS) {
        const unsigned v = buf[i];
        const int pos = atomicAdd(&cur[v >> 17], 1);
        stage[bs + pos] = v & 0x1FFFFu;        // strip dlocal: plain src
    }
    // Rescale this bucket's H rows: H *= dinv[node] (bf16 in place, coalesced).
    const int node0 = b * BKT;
    const int nn = min(BKT, N - node0);
    unsigned* Hrow = H2 + (size_t)node0 * 32;
    for (int i = t; i < nn * 32; i += THREADS) {
        const float di = dv[i >> 5];
        const unsigned v = Hrow[i];
        const float lo = bflo(v) * di;
        const float hi = bfhi(v) * di;
        Hrow[i] = ((unsigned)f2bf(hi) << 16) | (unsigned)f2bf(lo);
    }
}

// ---- Dense matmul (R10): Y = (X @ W) [*dinv] [+bias], bf16 or fp32 out -----

template <int K, int M, int TILE_R, bool BIAS, bool SCALE, bool OUT_BF16, typename OutT>
__global__ __launch_bounds__(THREADS) void mm_kernel(const float* __restrict__ X,
                                                     const float* __restrict__ W,
                                                     const float* __restrict__ bias,
                                                     const float* __restrict__ dinv,
                                                     OutT* __restrict__ Y, int N) {
    static_assert((TILE_R / 4) * (M / 4) == THREADS, "tile/thread mismatch");
    __shared__ float Ws[K * M];
    const int t = threadIdx.x;
    for (int i = t; i < K * M / 4; i += THREADS)
        ((float4*)Ws)[i] = ((const float4*)W)[i];
    __syncthreads();

    constexpr int CG = M / 4;
    const int rg = t / CG;
    const int cg = t % CG;
    const int r0 = blockIdx.x * TILE_R + rg * 4;
    const float* xp0 = X + (size_t)min(r0 + 0, N - 1) * K;
    const float* xp1 = X + (size_t)min(r0 + 1, N - 1) * K;
    const float* xp2 = X + (size_t)min(r0 + 2, N - 1) * K;
    const float* xp3 = X + (size_t)min(r0 + 3, N - 1) * K;
    const float* wb = &Ws[cg * 4];
    float acc[4][4] = {};

#define GCN_STEP(XV, WV)                                                                  \
    acc[0][0] = fmaf(xv0.XV, WV.x, acc[0][0]); acc[0][1] = fmaf(xv0.XV, WV.y, acc[0][1]); \
    acc[0][2] = fmaf(xv0.XV, WV.z, acc[0][2]); acc[0][3] = fmaf(xv0.XV, WV.w, acc[0][3]); \
    acc[1][0] = fmaf(xv1.XV, WV.x, acc[1][0]); acc[1][1] = fmaf(xv1.XV, WV.y, acc[1][1]); \
    acc[1][2] = fmaf(xv1.XV, WV.z, acc[1][2]); acc[1][3] = fmaf(xv1.XV, WV.w, acc[1][3]); \
    acc[2][0] = fmaf(xv2.XV, WV.x, acc[2][0]); acc[2][1] = fmaf(xv2.XV, WV.y, acc[2][1]); \
    acc[2][2] = fmaf(xv2.XV, WV.z, acc[2][2]); acc[2][3] = fmaf(xv2.XV, WV.w, acc[2][3]); \
    acc[3][0] = fmaf(xv3.XV, WV.x, acc[3][0]); acc[3][1] = fmaf(xv3.XV, WV.y, acc[3][1]); \
    acc[3][2] = fmaf(xv3.XV, WV.z, acc[3][2]); acc[3][3] = fmaf(xv3.XV, WV.w, acc[3][3]);

#define GCN_CHUNK(KK)                                                   \
    {                                                                   \
        const float4 wv0 = *(const float4*)(wb + (size_t)(KK + 0) * M); \
        const float4 wv1 = *(const float4*)(wb + (size_t)(KK + 1) * M); \
        const float4 wv2 = *(const float4*)(wb + (size_t)(KK + 2) * M); \
        const float4 wv3 = *(const float4*)(wb + (size_t)(KK + 3) * M); \
        GCN_STEP(x, wv0)                                                \
        GCN_STEP(y, wv1)                                                \
        GCN_STEP(z, wv2)                                                \
        GCN_STEP(w, wv3)                                                \
    }

    float4 A0 = *(const float4*)(xp0 + 0), A1 = *(const float4*)(xp1 + 0);
    float4 A2 = *(const float4*)(xp2 + 0), A3 = *(const float4*)(xp3 + 0);
    float4 B0 = *(const float4*)(xp0 + 4), B1 = *(const float4*)(xp1 + 4);
    float4 B2 = *(const float4*)(xp2 + 4), B3 = *(const float4*)(xp3 + 4);
#pragma unroll 4
    for (int k = 0; k < K; k += 4) {
        const float4 xv0 = A0, xv1 = A1, xv2 = A2, xv3 = A3;
        A0 = B0; A1 = B1; A2 = B2; A3 = B3;
        const int kn = min(k + 8, K - 4);
        B0 = *(const float4*)(xp0 + kn);
        B1 = *(const float4*)(xp1 + kn);
        B2 = *(const float4*)(xp2 + kn);
        B3 = *(const float4*)(xp3 + kn);
        GCN_CHUNK(k)
    }
#undef GCN_CHUNK
#undef GCN_STEP

#pragma unroll
    for (int i = 0; i < 4; ++i) {
        const int r = r0 + i;
        if (r < N) {
            float4 o = {acc[i][0], acc[i][1], acc[i][2], acc[i][3]};
            if (SCALE) {
                const float d = dinv[r];
                o.x *= d; o.y *= d; o.z *= d; o.w *= d;
            }
            if (BIAS) {
                o.x += bias[cg * 4 + 0]; o.y += bias[cg * 4 + 1];
                o.z += bias[cg * 4 + 2]; o.w += bias[cg * 4 + 3];
            }
            if (OUT_BF16) {
                ushort4 p = {f2bf(o.x), f2bf(o.y), f2bf(o.z), f2bf(o.w)};
                *(ushort4*)((ushort_t*)Y + (size_t)r * M + cg * 4) = p;
            } else {
                *(float4*)((float*)Y + (size_t)r * M + cg * 4) = o;
            }
        }
    }
}

// ---- Aggregation (R10): wave per node; lane owns a feature PAIR ------------

__global__ __launch_bounds__(THREADS) void agg_kernel(const unsigned* __restrict__ srt,
                                                      const int* __restrict__ row,
                                                      const float* __restrict__ dinv,
                                                      const unsigned* __restrict__ H2,  // [N][32] dwords (bf16 pairs)
                                                      const float* __restrict__ bias,
                                                      float* __restrict__ out, int N, int E) {
    const int idx = blockIdx.x * blockDim.x + threadIdx.x;
    const int node = idx >> 6;
    if (node >= N) return;
    const int l = threadIdx.x & 63;
    const int half = l >> 5;          // 0: edges 0-7 of chunk, 1: edges 8-15
    const int f2 = l & 31;            // feature pair (2*f2, 2*f2+1)
    const int start = row[node];
    const int end = (node + 1 < N) ? row[node + 1] : E;
    float acc0 = 0.0f, acc1 = 0.0f;

    int base = start;
    for (; base + 16 <= end; base += 16) {
        const unsigned* sp = srt + __builtin_amdgcn_readfirstlane(base);
        const unsigned g0 = sp[0],  g1 = sp[1],  g2 = sp[2],  g3 = sp[3];
        const unsigned g4 = sp[4],  g5 = sp[5],  g6 = sp[6],  g7 = sp[7];
        const unsigned h0 = sp[8],  h1 = sp[9],  h2 = sp[10], h3 = sp[11];
        const unsigned h4 = sp[12], h5 = sp[13], h6 = sp[14], h7 = sp[15];
        const unsigned e0 = half ? h0 : g0, e1 = half ? h1 : g1;
        const unsigned e2 = half ? h2 : g2, e3 = half ? h3 : g3;
        const unsigned e4 = half ? h4 : g4, e5 = half ? h5 : g5;
        const unsigned e6 = half ? h6 : g6, e7 = half ? h7 : g7;
        const unsigned v0 = H2[(size_t)e0 * 32 + f2];
        const unsigned v1 = H2[(size_t)e1 * 32 + f2];
        const unsigned v2 = H2[(size_t)e2 * 32 + f2];
        const unsigned v3 = H2[(size_t)e3 * 32 + f2];
        const unsigned v4 = H2[(size_t)e4 * 32 + f2];
        const unsigned v5 = H2[(size_t)e5 * 32 + f2];
        const unsigned v6 = H2[(size_t)e6 * 32 + f2];
        const unsigned v7 = H2[(size_t)e7 * 32 + f2];
        acc0 += bflo(v0); acc1 += bfhi(v0);
        acc0 += bflo(v1); acc1 += bfhi(v1);
        acc0 += bflo(v2); acc1 += bfhi(v2);
        acc0 += bflo(v3); acc1 += bfhi(v3);
        acc0 += bflo(v4); acc1 += bfhi(v4);
        acc0 += bflo(v5); acc1 += bfhi(v5);
        acc0 += bflo(v6); acc1 += bfhi(v6);
        acc0 += bflo(v7); acc1 += bfhi(v7);
    }
    if (base < end) {
        const unsigned* sp = srt + __builtin_amdgcn_readfirstlane(base);
        const unsigned cap = (unsigned)(N - 1);
        const int j0 = base + half * 8;
#pragma unroll
        for (int k = 0; k < 8; ++k) {
            const unsigned raw = half ? sp[8 + k] : sp[k];   // may be past end: in-ws garbage
            const bool ok = (j0 + k) < end;
            const unsigned s = min(raw & 0x1FFFFu, cap);     // clamp to valid H2 row
            const unsigned v = H2[(size_t)s * 32 + f2];
            acc0 += ok ? bflo(v) : 0.0f;
            acc1 += ok ? bfhi(v) : 0.0f;
        }
    }

    acc0 += __shfl_xor(acc0, 32, 64);
    acc1 += __shfl_xor(acc1, 32, 64);
    if (half == 0) {
        const unsigned sv = H2[(size_t)node * 32 + f2];   // self-loop row (already *dinv)
        const float d = dinv[node];
        const float2 b = *(const float2*)(bias + f2 * 2);
        const float o0 = fmaxf(fmaf(acc0 + bflo(sv), d, b.x), 0.0f);
        const float o1 = fmaxf(fmaf(acc1 + bfhi(sv), d, b.y), 0.0f);
        float2 o = {o0, o1};
        *(float2*)(out + (size_t)node * 64 + f2 * 2) = o;
    }
}

// ---- Launch ----------------------------------------------------------------

extern "C" void kernel_launch(void* const* d_in, const int* in_sizes, int n_in,
                              void* d_out, int out_size, void* d_ws, size_t ws_size,
                              hipStream_t stream) {
    const float* x   = (const float*)d_in[0];
    const int*   ei  = (const int*)d_in[1];   // [2, E] int32
    const float* W1  = (const float*)d_in[3];
    const float* b1  = (const float*)d_in[4];
    const float* W2  = (const float*)d_in[5];
    const float* b2  = (const float*)d_in[6];
    const float* Wfc = (const float*)d_in[7];
    const float* bfc = (const float*)d_in[8];
    float* out = (float*)d_out;

    const int N = in_sizes[0] / 128;
    const int E = in_sizes[1] / 2;
    const int* src = ei;
    const int* dst = ei + E;

    const int nb   = (N + BKT - 1) / BKT;     // 391 buckets
    const int nblk = (E + EPB - 1) / EPB;     // 391 edge-chunks

    // ws: bh[nb*nblk] | btot[nb] | bstart[nb+1] | stage[E] | row[N] | dinv[N]
    //     | bufF[N*64] fp32 | bufH[N*64] bf16   (~46 MB)
    int*      bh     = (int*)d_ws;
    int*      btot   = bh + (size_t)nb * nblk;
    int*      bstart = btot + nb;
    unsigned* stage  = (unsigned*)(bstart + nb + 1);
    int*      row    = (int*)(stage + E);
    float*    dinv   = (float*)(row + N);
    float*    bufF   = dinv + N;                             // fp32 [N,64]
    ushort_t* bufH   = (ushort_t*)(bufF + (size_t)N * 64);   // bf16 [N,64]

    const int gW = ((N * 64) + THREADS - 1) / THREADS;  // one wave per node
    const int mmB = (N + 63) / 64;

    // 1) Fused: hist (nblk blocks) + mm1 unscaled bf16 (mmB blocks).
    mmh_kernel<128, 64, 64><<<nblk + mmB, THREADS, 0, stream>>>(
        x, W1, bufH, N, dst, E, nb, nblk, bh);
    // 2) Row-relative offsets + bucket totals.
    scanS_kernel<<<nb, THREADS, 0, stream>>>(bh, nb, nblk, btot);
    // 3) Bin edges (inline bucket-total scan; block 0 writes bstart).
    binB_kernel<<<nblk, BIN_T, 0, stream>>>(src, dst, E, nb, nblk, bh, btot, bstart, stage);
    // 4) Sort buckets; compute row/dinv; rescale layer-1 H by dinv.
    sortB_kernel<<<nb, THREADS, 0, stream>>>(stage, bstart, nb, N, row, dinv, (unsigned*)bufH);
    // 5) Layer-1 aggregate.
    agg_kernel<<<gW, THREADS, 0, stream>>>(stage, row, dinv, (const unsigned*)bufH, b1, bufF, N, E);
    // 6) Layer 2 matmul (scaled inline, bf16 out).
    mm_kernel<64, 64, 64, false, true, true><<<mmB, THREADS, 0, stream>>>(
        bufF, W2, nullptr, dinv, bufH, N);
    // 7) Layer-2 aggregate.
    agg_kernel<<<gW, THREADS, 0, stream>>>(stage, row, dinv, (const unsigned*)bufH, b2, bufF, N, E);
    // 8) FC.
    mm_kernel<64, 32, 128, true, false, false><<<(N + 127) / 128, THREADS, 0, stream>>>(
        bufF, Wfc, bfc, nullptr, out, N);
}

// Round 13
// 256.454 us; speedup vs baseline: 2.2758x; 1.1653x over previous
//
#include <hip/hip_runtime.h>

// GCN: 2x (GCNConv + ReLU) + FC.  N=100000, E=1600000, F: 128 -> 64 -> 64 -> 32. fp32.
//
// R13: matmuls moved to MFMA (mfma_f32_16x16x32_bf16). Every FMA mm variant
// (R8 LDS-staged, R9/R10 streamed, R11 lane-swap) plateaued at ~50 us because
// vector-FMA needs full K rows per thread -> broadcast loads or barrier-staged
// LDS. With MFMA the compute is ~16 mfma/wave and mm1 becomes a coalesced
// 51.2 MB stream.  Fragment layouts (guide-verified): A[m=lane&15][k=q*8+j],
// B from W^T[n=lane&15][k=q*8+j], C/D col=lane&15,row=q*4+reg; C goes through
// LDS for coalesced stores.  agg now writes relu outputs in bf16 -> mm2/fc
// read bf16 (half traffic).  W^T bf16 prep fused into hist kernel.
// Partition passes (R6/R12), agg gather core (R10) unchanged.

#define THREADS 256
#define BIN_T 512
#define EPB 4096
#define BKT 256
#define SORT_CAP 8192

typedef unsigned short ushort_t;
typedef __attribute__((ext_vector_type(8))) short short8;
typedef __attribute__((ext_vector_type(4))) float f32x4;

__device__ __forceinline__ ushort_t f2bf(float f) {  // round-to-nearest-even
    unsigned u = __float_as_uint(f);
    u += 0x7FFFu + ((u >> 16) & 1u);
    return (ushort_t)(u >> 16);
}
__device__ __forceinline__ float bflo(unsigned v) { return __uint_as_float(v << 16); }
__device__ __forceinline__ float bfhi(unsigned v) { return __uint_as_float(v & 0xFFFF0000u); }

// ---- Kernel 1: hist blocks + W-transpose/bf16 blocks -----------------------

__global__ __launch_bounds__(THREADS) void histW_kernel(const int* __restrict__ dst, int E,
                                                        int nb, int nblk, int* __restrict__ bh,
                                                        const float* __restrict__ W1,
                                                        const float* __restrict__ W2,
                                                        const float* __restrict__ Wfc,
                                                        ushort_t* __restrict__ WT1,
                                                        ushort_t* __restrict__ WT2,
                                                        ushort_t* __restrict__ WTfc) {
    const int t = threadIdx.x;
    if ((int)blockIdx.x < nblk) {
        __shared__ int h[512];
        for (int i = t; i < nb; i += THREADS) h[i] = 0;
        __syncthreads();
        const int e0 = blockIdx.x * EPB;
        const int e1 = min(e0 + EPB, E);
        for (int e = e0 + t; e < e1; e += THREADS)
            atomicAdd(&h[dst[e] >> 8], 1);
        __syncthreads();
        for (int i = t; i < nb; i += THREADS)
            bh[(size_t)i * nblk + blockIdx.x] = h[i];
        return;
    }
    // W^T bf16 prep: WT[m*K+k] = bf16(W[k*M+m]).  28 slice-blocks of 512 elems.
    const int wb = blockIdx.x - nblk;
    const float* W; ushort_t* WT; int M, K, base;
    if (wb < 16)      { W = W1;  WT = WT1;  M = 64; K = 128; base = wb * 512; }
    else if (wb < 24) { W = W2;  WT = WT2;  M = 64; K = 64;  base = (wb - 16) * 512; }
    else              { W = Wfc; WT = WTfc; M = 32; K = 64;  base = (wb - 24) * 512; }
    for (int e = base + t; e < base + 512; e += THREADS) {
        const int m = e / K, k = e % K;
        WT[e] = f2bf(W[(size_t)k * M + m]);
    }
}

// ---- Pass 2: per-bucket row scan ------------------------------------------

__global__ __launch_bounds__(THREADS) void scanS_kernel(int* __restrict__ bh,
                                                        int nb, int nblk,
                                                        int* __restrict__ btot) {
    __shared__ int s[THREADS];
    const int b = blockIdx.x, t = threadIdx.x;
    int* rowp = bh + (size_t)b * nblk;
    const int run = (nblk + THREADS - 1) / THREADS;
    const int lo = min(t * run, nblk), hi = min(lo + run, nblk);
    int v[4];
    int sum = 0;
    for (int i = lo; i < hi; ++i) { v[i - lo] = rowp[i]; sum += v[i - lo]; }
    s[t] = sum;
    __syncthreads();
    for (int off = 1; off < THREADS; off <<= 1) {
        int u = (t >= off) ? s[t - off] : 0;
        __syncthreads();
        s[t] += u;
        __syncthreads();
    }
    int pre = s[t] - sum;
    for (int i = lo; i < hi; ++i) { rowp[i] = pre; pre += v[i - lo]; }
    if (t == THREADS - 1) btot[b] = s[t];
}

// ---- Pass 3: bin edges (inline bucket-total scan) --------------------------

__global__ __launch_bounds__(BIN_T) void binB_kernel(const int* __restrict__ src,
                                                     const int* __restrict__ dst, int E,
                                                     int nb, int nblk,
                                                     const int* __restrict__ bh,
                                                     const int* __restrict__ btot,
                                                     int* __restrict__ bstart,
                                                     unsigned* __restrict__ stage) {
    __shared__ int s[BIN_T];
    __shared__ int cur[BIN_T];
    const int t = threadIdx.x;
    const int v = (t < nb) ? btot[t] : 0;
    s[t] = v;
    __syncthreads();
    for (int off = 1; off < BIN_T; off <<= 1) {
        int u = (t >= off) ? s[t - off] : 0;
        __syncthreads();
        s[t] += u;
        __syncthreads();
    }
    const int base = s[t] - v;
    if (t < nb) cur[t] = base + bh[(size_t)t * nblk + blockIdx.x];
    if (blockIdx.x == 0) {
        if (t < nb) bstart[t] = base;
        if (t == 0) bstart[nb] = E;
    }
    __syncthreads();
    const int e0 = blockIdx.x * EPB;
    const int e1 = min(e0 + EPB, E);
    for (int e = e0 + t; e < e1; e += BIN_T) {
        const int d = dst[e];
        const int pos = atomicAdd(&cur[d >> 8], 1);
        stage[pos] = ((unsigned)(d & (BKT - 1)) << 17) | (unsigned)src[e];
    }
}

// ---- Pass 4: per-bucket counting sort + row/dinv + H1 rescale --------------

__global__ __launch_bounds__(THREADS) void sortB_kernel(unsigned* __restrict__ stage,
                                                        const int* __restrict__ bstart,
                                                        int nb, int N,
                                                        int* __restrict__ row,
                                                        float* __restrict__ dinv,
                                                        unsigned* __restrict__ H2) {
    __shared__ unsigned buf[SORT_CAP];
    __shared__ int cnt[BKT], cur[BKT], scn[BKT];
    __shared__ float dv[BKT];
    const int b = blockIdx.x, t = threadIdx.x;
    const int bs = bstart[b];
    const int be = bstart[b + 1];
    const int m = be - bs;
    cnt[t] = 0;
    __syncthreads();
    for (int i = t; i < m; i += THREADS) {
        const unsigned v = stage[bs + i];
        buf[i] = v;
        atomicAdd(&cnt[v >> 17], 1);
    }
    __syncthreads();
    const int c = cnt[t];
    scn[t] = c;
    __syncthreads();
    for (int off = 1; off < BKT; off <<= 1) {
        int u = (t >= off) ? scn[t - off] : 0;
        __syncthreads();
        scn[t] += u;
        __syncthreads();
    }
    const int excl = scn[t] - c;
    cur[t] = excl;
    const float d = rsqrtf((float)c + 1.0f);
    dv[t] = d;
    const int node = b * BKT + t;
    if (node < N) {
        row[node] = bs + excl;
        dinv[node] = d;
    }
    __syncthreads();
    for (int i = t; i < m; i += THREADS) {
        const unsigned v = buf[i];
        const int pos = atomicAdd(&cur[v >> 17], 1);
        stage[bs + pos] = v & 0x1FFFFu;
    }
    // Rescale this bucket's H1 rows by dinv (deferred layer-1 scaling).
    const int node0 = b * BKT;
    const int nn = min(BKT, N - node0);
    unsigned* Hrow = H2 + (size_t)node0 * 32;
    for (int i = t; i < nn * 32; i += THREADS) {
        const float di = dv[i >> 5];
        const unsigned v = Hrow[i];
        const float lo = bflo(v) * di;
        const float hi = bfhi(v) * di;
        Hrow[i] = ((unsigned)f2bf(hi) << 16) | (unsigned)f2bf(lo);
    }
}

// ---- MFMA matmul: Y[N,M] = X[N,K] @ W[K,M] ---------------------------------
// MODE 0: X fp32 -> bf16 out (unscaled, mm1).  MODE 1: X bf16 -> bf16 out
// *dinv (mm2).  MODE 2: X bf16 -> f32 out +bias (fc).  W passed as W^T bf16
// [M][K].  64-row tile/block, wave w owns rows w*16..w*16+15, M/16 col-tiles,
// K/32 mfma steps.  C staged through LDS for coalesced stores.

template <int K, int M, int MODE>
__global__ __launch_bounds__(THREADS) void mm_mfma_kernel(const float* __restrict__ Xf,
                                                          const ushort_t* __restrict__ Xh,
                                                          const ushort_t* __restrict__ WT,
                                                          const float* __restrict__ dinv,
                                                          const float* __restrict__ bias,
                                                          void* __restrict__ Yv, int N) {
    constexpr bool INF32 = (MODE == 0);
    constexpr int XROW = INF32 ? (K + 4) : (K + 8);    // padded row stride (elems)
    constexpr int XB = 64 * XROW * (INF32 ? 4 : 2);
    constexpr int WROW = K + 8;
    constexpr int WB = M * WROW * 2;
    constexpr int CB = 64 * M * 4;
    constexpr int SMEM = (XB + WB > CB) ? (XB + WB) : CB;
    __shared__ __align__(16) char smem[SMEM];
    const int t = threadIdx.x;
    const int row0 = blockIdx.x * 64;

    // Stage W^T [M][K] bf16 -> LDS (padded rows), coalesced 16 B chunks.
    ushort_t* WsU = (ushort_t*)(smem + XB);
    for (int i = t; i < M * K / 8; i += THREADS) {
        const int m = i / (K / 8), kc = i % (K / 8);
        *(uint4*)(WsU + m * WROW + kc * 8) = ((const uint4*)WT)[i];
    }
    // Stage X tile (64 rows), coalesced 16 B chunks; OOB rows clamp to N-1.
    if (INF32) {
        float* XsF = (float*)smem;
        for (int i = t; i < 64 * K / 4; i += THREADS) {
            const int r = i / (K / 4), kc = i % (K / 4);
            const int gr = min(row0 + r, N - 1);
            *(float4*)(XsF + r * XROW + kc * 4) = *(const float4*)(Xf + (size_t)gr * K + kc * 4);
        }
    } else {
        ushort_t* XsU = (ushort_t*)smem;
        for (int i = t; i < 64 * K / 8; i += THREADS) {
            const int r = i / (K / 8), kc = i % (K / 8);
            const int gr = min(row0 + r, N - 1);
            *(uint4*)(XsU + r * XROW + kc * 8) = *(const uint4*)(Xh + (size_t)gr * K + kc * 8);
        }
    }
    __syncthreads();

    const int w = t >> 6, lane = t & 63;
    const int m0 = w * 16, lm = lane & 15, q = lane >> 4;
    f32x4 acc[M / 16];
#pragma unroll
    for (int c = 0; c < M / 16; ++c) acc[c] = (f32x4)0.0f;

#pragma unroll
    for (int s = 0; s < K / 32; ++s) {
        short8 a;
        if (INF32) {
            const float* xr = (const float*)smem + (size_t)(m0 + lm) * XROW + s * 32 + q * 8;
            const float4 f0 = *(const float4*)xr;
            const float4 f1 = *(const float4*)(xr + 4);
            a[0] = (short)f2bf(f0.x); a[1] = (short)f2bf(f0.y);
            a[2] = (short)f2bf(f0.z); a[3] = (short)f2bf(f0.w);
            a[4] = (short)f2bf(f1.x); a[5] = (short)f2bf(f1.y);
            a[6] = (short)f2bf(f1.z); a[7] = (short)f2bf(f1.w);
        } else {
            a = *(const short8*)((const ushort_t*)smem + (size_t)(m0 + lm) * XROW + s * 32 + q * 8);
        }
#pragma unroll
        for (int c = 0; c < M / 16; ++c) {
            const short8 b = *(const short8*)(WsU + (size_t)(c * 16 + lm) * WROW + s * 32 + q * 8);
            acc[c] = __builtin_amdgcn_mfma_f32_16x16x32_bf16(a, b, acc[c], 0, 0, 0);
        }
    }
    __syncthreads();   // Xs/Ws dead; reuse as C [64][M] f32
    float* Cs = (float*)smem;
#pragma unroll
    for (int c = 0; c < M / 16; ++c)
#pragma unroll
        for (int r = 0; r < 4; ++r)
            Cs[(size_t)(m0 + q * 4 + r) * M + c * 16 + lm] = acc[c][r];
    __syncthreads();

    for (int g = t; g < 64 * M / 4; g += THREADS) {
        const int r = g / (M / 4);
        const int gr = row0 + r;
        if (gr >= N) continue;
        float4 o = *(const float4*)(Cs + (size_t)g * 4);
        const int col = (g % (M / 4)) * 4;
        if (MODE == 1) {
            const float d = dinv[gr];
            o.x *= d; o.y *= d; o.z *= d; o.w *= d;
        }
        if (MODE == 2) {
            o.x += bias[col]; o.y += bias[col + 1]; o.z += bias[col + 2]; o.w += bias[col + 3];
            *(float4*)((float*)Yv + (size_t)gr * M + col) = o;
        } else {
            ushort4 pk = {f2bf(o.x), f2bf(o.y), f2bf(o.z), f2bf(o.w)};
            *(ushort4*)((ushort_t*)Yv + (size_t)gr * M + col) = pk;
        }
    }
}

// ---- Aggregation (R10 core): wave per node, pair-gather, bf16 out ----------

__global__ __launch_bounds__(THREADS) void agg_kernel(const unsigned* __restrict__ srt,
                                                      const int* __restrict__ row,
                                                      const float* __restrict__ dinv,
                                                      const unsigned* __restrict__ H2,  // [N][32] bf16 pairs
                                                      const float* __restrict__ bias,
                                                      unsigned* __restrict__ out2,      // [N][32] bf16 pairs
                                                      int N, int E) {
    const int idx = blockIdx.x * blockDim.x + threadIdx.x;
    const int node = idx >> 6;
    if (node >= N) return;
    const int l = threadIdx.x & 63;
    const int half = l >> 5;
    const int f2 = l & 31;
    const int start = row[node];
    const int end = (node + 1 < N) ? row[node + 1] : E;
    float acc0 = 0.0f, acc1 = 0.0f;

    int base = start;
    for (; base + 16 <= end; base += 16) {
        const unsigned* sp = srt + __builtin_amdgcn_readfirstlane(base);
        const unsigned g0 = sp[0],  g1 = sp[1],  g2 = sp[2],  g3 = sp[3];
        const unsigned g4 = sp[4],  g5 = sp[5],  g6 = sp[6],  g7 = sp[7];
        const unsigned h0 = sp[8],  h1 = sp[9],  h2 = sp[10], h3 = sp[11];
        const unsigned h4 = sp[12], h5 = sp[13], h6 = sp[14], h7 = sp[15];
        const unsigned e0 = half ? h0 : g0, e1 = half ? h1 : g1;
        const unsigned e2 = half ? h2 : g2, e3 = half ? h3 : g3;
        const unsigned e4 = half ? h4 : g4, e5 = half ? h5 : g5;
        const unsigned e6 = half ? h6 : g6, e7 = half ? h7 : g7;
        const unsigned v0 = H2[(size_t)e0 * 32 + f2];
        const unsigned v1 = H2[(size_t)e1 * 32 + f2];
        const unsigned v2 = H2[(size_t)e2 * 32 + f2];
        const unsigned v3 = H2[(size_t)e3 * 32 + f2];
        const unsigned v4 = H2[(size_t)e4 * 32 + f2];
        const unsigned v5 = H2[(size_t)e5 * 32 + f2];
        const unsigned v6 = H2[(size_t)e6 * 32 + f2];
        const unsigned v7 = H2[(size_t)e7 * 32 + f2];
        acc0 += bflo(v0); acc1 += bfhi(v0);
        acc0 += bflo(v1); acc1 += bfhi(v1);
        acc0 += bflo(v2); acc1 += bfhi(v2);
        acc0 += bflo(v3); acc1 += bfhi(v3);
        acc0 += bflo(v4); acc1 += bfhi(v4);
        acc0 += bflo(v5); acc1 += bfhi(v5);
        acc0 += bflo(v6); acc1 += bfhi(v6);
        acc0 += bflo(v7); acc1 += bfhi(v7);
    }
    if (base < end) {
        const unsigned* sp = srt + __builtin_amdgcn_readfirstlane(base);
        const unsigned cap = (unsigned)(N - 1);
        const int j0 = base + half * 8;
#pragma unroll
        for (int k = 0; k < 8; ++k) {
            const unsigned raw = half ? sp[8 + k] : sp[k];   // may read past end: padded ws, safe
            const bool ok = (j0 + k) < end;
            const unsigned s = min(raw & 0x1FFFFu, cap);
            const unsigned v = H2[(size_t)s * 32 + f2];
            acc0 += ok ? bflo(v) : 0.0f;
            acc1 += ok ? bfhi(v) : 0.0f;
        }
    }

    acc0 += __shfl_xor(acc0, 32, 64);
    acc1 += __shfl_xor(acc1, 32, 64);
    if (half == 0) {
        const unsigned sv = H2[(size_t)node * 32 + f2];   // self-loop row (already *dinv)
        const float d = dinv[node];
        const float2 b = *(const float2*)(bias + f2 * 2);
        const float o0 = fmaxf(fmaf(acc0 + bflo(sv), d, b.x), 0.0f);
        const float o1 = fmaxf(fmaf(acc1 + bfhi(sv), d, b.y), 0.0f);
        out2[(size_t)node * 32 + f2] = ((unsigned)f2bf(o1) << 16) | (unsigned)f2bf(o0);
    }
}

// ---- Launch ----------------------------------------------------------------

extern "C" void kernel_launch(void* const* d_in, const int* in_sizes, int n_in,
                              void* d_out, int out_size, void* d_ws, size_t ws_size,
                              hipStream_t stream) {
    const float* x   = (const float*)d_in[0];
    const int*   ei  = (const int*)d_in[1];   // [2, E] int32
    const float* W1  = (const float*)d_in[3];
    const float* b1  = (const float*)d_in[4];
    const float* W2  = (const float*)d_in[5];
    const float* b2  = (const float*)d_in[6];
    const float* Wfc = (const float*)d_in[7];
    const float* bfc = (const float*)d_in[8];
    float* out = (float*)d_out;

    const int N = in_sizes[0] / 128;
    const int E = in_sizes[1] / 2;
    const int* src = ei;
    const int* dst = ei + E;

    const int nb   = (N + BKT - 1) / BKT;     // 391 buckets
    const int nblk = (E + EPB - 1) / EPB;     // 391 edge-chunks

    // Workspace (256 B-aligned slices; ~34 MB).
    char* p = (char*)d_ws;
    auto alloc = [&](size_t bytes) { char* r = p; p += (bytes + 255) & ~(size_t)255; return r; };
    int*      bh     = (int*)alloc((size_t)nb * nblk * 4);
    int*      btot   = (int*)alloc((size_t)nb * 4);
    int*      bstart = (int*)alloc((size_t)(nb + 1) * 4);
    unsigned* stage  = (unsigned*)alloc((size_t)E * 4);
    int*      row    = (int*)alloc((size_t)N * 4);
    float*    dinv   = (float*)alloc((size_t)N * 4);
    ushort_t* WT1    = (ushort_t*)alloc(64 * 128 * 2);
    ushort_t* WT2    = (ushort_t*)alloc(64 * 64 * 2);
    ushort_t* WTfc   = (ushort_t*)alloc(32 * 64 * 2);
    ushort_t* bufH   = (ushort_t*)alloc((size_t)N * 64 * 2);   // H tables (bf16)
    ushort_t* bufR   = (ushort_t*)alloc((size_t)N * 64 * 2);   // relu outputs (bf16)

    const int gW  = ((N * 64) + THREADS - 1) / THREADS;  // one wave per node
    const int mmB = (N + 63) / 64;

    // 1) hist + W^T bf16 prep.
    histW_kernel<<<nblk + 28, THREADS, 0, stream>>>(dst, E, nb, nblk, bh,
                                                    W1, W2, Wfc, WT1, WT2, WTfc);
    // 2) mm1 (MFMA, fp32 in, unscaled bf16 out).
    mm_mfma_kernel<128, 64, 0><<<mmB, THREADS, 0, stream>>>(
        x, nullptr, WT1, nullptr, nullptr, bufH, N);
    // 3-5) partition -> sorted CSR; sortB rescales H1 by dinv.
    scanS_kernel<<<nb, THREADS, 0, stream>>>(bh, nb, nblk, btot);
    binB_kernel<<<nblk, BIN_T, 0, stream>>>(src, dst, E, nb, nblk, bh, btot, bstart, stage);
    sortB_kernel<<<nb, THREADS, 0, stream>>>(stage, bstart, nb, N, row, dinv, (unsigned*)bufH);
    // 6) layer-1 aggregate -> relu1 bf16.
    agg_kernel<<<gW, THREADS, 0, stream>>>(stage, row, dinv, (const unsigned*)bufH, b1,
                                           (unsigned*)bufR, N, E);
    // 7) mm2 (MFMA, bf16 in, *dinv bf16 out).
    mm_mfma_kernel<64, 64, 1><<<mmB, THREADS, 0, stream>>>(
        nullptr, bufR, WT2, dinv, nullptr, bufH, N);
    // 8) layer-2 aggregate -> relu2 bf16.
    agg_kernel<<<gW, THREADS, 0, stream>>>(stage, row, dinv, (const unsigned*)bufH, b2,
                                           (unsigned*)bufR, N, E);
    // 9) FC (MFMA, bf16 in, f32 out + bias).
    mm_mfma_kernel<64, 32, 2><<<mmB, THREADS, 0, stream>>>(
        nullptr, bufR, WTfc, nullptr, bfc, out, N);
}

// Round 14
// 252.899 us; speedup vs baseline: 2.3078x; 1.0141x over previous
//
#include <hip/hip_runtime.h>

// GCN: 2x (GCNConv + ReLU) + FC.  N=100000, E=1600000, F: 128 -> 64 -> 64 -> 32. fp32.
//
// R14 (on R13's MFMA structure):
//  - agg: 32-bit gather indexing ((e<<5)+f2, unsigned) -> saddr+voffset loads;
//    R13's (size_t) indexing emitted 64-bit addr chains (VALUBusy 64%).
//  - hist re-fused into mm1 (R12: hist rides free in mm1 stalls).
//  - WT prep kernel dropped: every mm kernel transposes+cvts its fp32 W into
//    LDS at staging time (W is L2-resident, 8-32 KB).
// Partition (R6/R12), agg core (R10/R13), MFMA mm (R13) otherwise unchanged.

#define THREADS 256
#define BIN_T 512
#define EPB 4096
#define BKT 256
#define SORT_CAP 8192

typedef unsigned short ushort_t;
typedef __attribute__((ext_vector_type(8))) short short8;
typedef __attribute__((ext_vector_type(4))) float f32x4;

__device__ __forceinline__ ushort_t f2bf(float f) {  // round-to-nearest-even
    unsigned u = __float_as_uint(f);
    u += 0x7FFFu + ((u >> 16) & 1u);
    return (ushort_t)(u >> 16);
}
__device__ __forceinline__ float bflo(unsigned v) { return __uint_as_float(v << 16); }
__device__ __forceinline__ float bfhi(unsigned v) { return __uint_as_float(v & 0xFFFF0000u); }

// ---- MFMA matmul (+optional fused histogram blocks) ------------------------
// HIST: blocks [0,nblk) do the per-(block,bucket) dst-histogram, rest do mm.
// MODE 0: X fp32 -> bf16 out (unscaled).  MODE 1: X bf16 -> bf16 out *dinv.
// MODE 2: X bf16 -> f32 out +bias.  W is fp32 [K][M], transposed+cvt to bf16
// LDS at staging.  64-row tile, wave w: rows w*16..w*16+15; K/32 mfma steps.
// C staged through LDS for coalesced stores.

template <int K, int M, int MODE, bool HIST>
__global__ __launch_bounds__(THREADS) void mm_mfma_kernel(const float* __restrict__ Xf,
                                                          const ushort_t* __restrict__ Xh,
                                                          const float* __restrict__ W,
                                                          const float* __restrict__ dinv,
                                                          const float* __restrict__ bias,
                                                          void* __restrict__ Yv, int N,
                                                          const int* __restrict__ dst, int E,
                                                          int nb, int nblk,
                                                          int* __restrict__ bh) {
    constexpr bool INF32 = (MODE == 0);
    constexpr int XROW = INF32 ? (K + 4) : (K + 8);
    constexpr int XB = 64 * XROW * (INF32 ? 4 : 2);
    constexpr int WROW = K + 8;
    constexpr int WB = M * WROW * 2;
    constexpr int CB = 64 * M * 4;
    constexpr int SMEM = (XB + WB > CB) ? (XB + WB) : CB;
    __shared__ __align__(16) char smem[SMEM];
    const int t = threadIdx.x;

    if (HIST && (int)blockIdx.x < nblk) {
        int* h = (int*)smem;
        for (int i = t; i < nb; i += THREADS) h[i] = 0;
        __syncthreads();
        const int e0 = blockIdx.x * EPB;
        const int e1 = min(e0 + EPB, E);
        for (int e = e0 + t; e < e1; e += THREADS)
            atomicAdd(&h[dst[e] >> 8], 1);
        __syncthreads();
        for (int i = t; i < nb; i += THREADS)
            bh[(size_t)i * nblk + blockIdx.x] = h[i];
        return;
    }
    const int row0 = (HIST ? (int)blockIdx.x - nblk : (int)blockIdx.x) * 64;

    // Stage W^T bf16 into LDS: read W[k][m] fp32 coalesced, write transposed.
    ushort_t* WsU = (ushort_t*)(smem + XB);
    for (int i = t; i < K * M; i += THREADS) {
        const int k = i / M, m = i % M;
        WsU[m * WROW + k] = f2bf(W[i]);
    }
    // Stage X tile (64 rows), coalesced 16 B chunks; OOB rows clamp to N-1.
    if (INF32) {
        float* XsF = (float*)smem;
        for (int i = t; i < 64 * K / 4; i += THREADS) {
            const int r = i / (K / 4), kc = i % (K / 4);
            const unsigned gr = (unsigned)min(row0 + r, N - 1);
            *(float4*)(XsF + r * XROW + kc * 4) = *(const float4*)(Xf + (size_t)gr * K + kc * 4);
        }
    } else {
        ushort_t* XsU = (ushort_t*)smem;
        for (int i = t; i < 64 * K / 8; i += THREADS) {
            const int r = i / (K / 8), kc = i % (K / 8);
            const unsigned gr = (unsigned)min(row0 + r, N - 1);
            *(uint4*)(XsU + r * XROW + kc * 8) = *(const uint4*)(Xh + (size_t)gr * K + kc * 8);
        }
    }
    __syncthreads();

    const int w = t >> 6, lane = t & 63;
    const int m0 = w * 16, lm = lane & 15, q = lane >> 4;
    f32x4 acc[M / 16];
#pragma unroll
    for (int c = 0; c < M / 16; ++c) acc[c] = (f32x4)0.0f;

#pragma unroll
    for (int s = 0; s < K / 32; ++s) {
        short8 a;
        if (INF32) {
            const float* xr = (const float*)smem + (size_t)(m0 + lm) * XROW + s * 32 + q * 8;
            const float4 f0 = *(const float4*)xr;
            const float4 f1 = *(const float4*)(xr + 4);
            a[0] = (short)f2bf(f0.x); a[1] = (short)f2bf(f0.y);
            a[2] = (short)f2bf(f0.z); a[3] = (short)f2bf(f0.w);
            a[4] = (short)f2bf(f1.x); a[5] = (short)f2bf(f1.y);
            a[6] = (short)f2bf(f1.z); a[7] = (short)f2bf(f1.w);
        } else {
            a = *(const short8*)((const ushort_t*)smem + (size_t)(m0 + lm) * XROW + s * 32 + q * 8);
        }
#pragma unroll
        for (int c = 0; c < M / 16; ++c) {
            const short8 b = *(const short8*)(WsU + (size_t)(c * 16 + lm) * WROW + s * 32 + q * 8);
            acc[c] = __builtin_amdgcn_mfma_f32_16x16x32_bf16(a, b, acc[c], 0, 0, 0);
        }
    }
    __syncthreads();   // Xs/Ws dead; reuse as C [64][M] f32
    float* Cs = (float*)smem;
#pragma unroll
    for (int c = 0; c < M / 16; ++c)
#pragma unroll
        for (int r = 0; r < 4; ++r)
            Cs[(size_t)(m0 + q * 4 + r) * M + c * 16 + lm] = acc[c][r];
    __syncthreads();

    for (int g = t; g < 64 * M / 4; g += THREADS) {
        const int r = g / (M / 4);
        const int gr = row0 + r;
        if (gr >= N) continue;
        float4 o = *(const float4*)(Cs + (size_t)g * 4);
        const int col = (g % (M / 4)) * 4;
        if (MODE == 1) {
            const float d = dinv[gr];
            o.x *= d; o.y *= d; o.z *= d; o.w *= d;
        }
        if (MODE == 2) {
            o.x += bias[col]; o.y += bias[col + 1]; o.z += bias[col + 2]; o.w += bias[col + 3];
            *(float4*)((float*)Yv + (size_t)gr * M + col) = o;
        } else {
            ushort4 pk = {f2bf(o.x), f2bf(o.y), f2bf(o.z), f2bf(o.w)};
            *(ushort4*)((ushort_t*)Yv + (size_t)gr * M + col) = pk;
        }
    }
}

// ---- Pass 2: per-bucket row scan ------------------------------------------

__global__ __launch_bounds__(THREADS) void scanS_kernel(int* __restrict__ bh,
                                                        int nb, int nblk,
                                                        int* __restrict__ btot) {
    __shared__ int s[THREADS];
    const int b = blockIdx.x, t = threadIdx.x;
    int* rowp = bh + (size_t)b * nblk;
    const int run = (nblk + THREADS - 1) / THREADS;
    const int lo = min(t * run, nblk), hi = min(lo + run, nblk);
    int v[4];
    int sum = 0;
    for (int i = lo; i < hi; ++i) { v[i - lo] = rowp[i]; sum += v[i - lo]; }
    s[t] = sum;
    __syncthreads();
    for (int off = 1; off < THREADS; off <<= 1) {
        int u = (t >= off) ? s[t - off] : 0;
        __syncthreads();
        s[t] += u;
        __syncthreads();
    }
    int pre = s[t] - sum;
    for (int i = lo; i < hi; ++i) { rowp[i] = pre; pre += v[i - lo]; }
    if (t == THREADS - 1) btot[b] = s[t];
}

// ---- Pass 3: bin edges (inline bucket-total scan) --------------------------

__global__ __launch_bounds__(BIN_T) void binB_kernel(const int* __restrict__ src,
                                                     const int* __restrict__ dst, int E,
                                                     int nb, int nblk,
                                                     const int* __restrict__ bh,
                                                     const int* __restrict__ btot,
                                                     int* __restrict__ bstart,
                                                     unsigned* __restrict__ stage) {
    __shared__ int s[BIN_T];
    __shared__ int cur[BIN_T];
    const int t = threadIdx.x;
    const int v = (t < nb) ? btot[t] : 0;
    s[t] = v;
    __syncthreads();
    for (int off = 1; off < BIN_T; off <<= 1) {
        int u = (t >= off) ? s[t - off] : 0;
        __syncthreads();
        s[t] += u;
        __syncthreads();
    }
    const int base = s[t] - v;
    if (t < nb) cur[t] = base + bh[(size_t)t * nblk + blockIdx.x];
    if (blockIdx.x == 0) {
        if (t < nb) bstart[t] = base;
        if (t == 0) bstart[nb] = E;
    }
    __syncthreads();
    const int e0 = blockIdx.x * EPB;
    const int e1 = min(e0 + EPB, E);
    for (int e = e0 + t; e < e1; e += BIN_T) {
        const int d = dst[e];
        const int pos = atomicAdd(&cur[d >> 8], 1);
        stage[pos] = ((unsigned)(d & (BKT - 1)) << 17) | (unsigned)src[e];
    }
}

// ---- Pass 4: per-bucket counting sort + row/dinv + H1 rescale --------------

__global__ __launch_bounds__(THREADS) void sortB_kernel(unsigned* __restrict__ stage,
                                                        const int* __restrict__ bstart,
                                                        int nb, int N,
                                                        int* __restrict__ row,
                                                        float* __restrict__ dinv,
                                                        unsigned* __restrict__ H2) {
    __shared__ unsigned buf[SORT_CAP];
    __shared__ int cnt[BKT], cur[BKT], scn[BKT];
    __shared__ float dv[BKT];
    const int b = blockIdx.x, t = threadIdx.x;
    const int bs = bstart[b];
    const int be = bstart[b + 1];
    const int m = be - bs;
    cnt[t] = 0;
    __syncthreads();
    for (int i = t; i < m; i += THREADS) {
        const unsigned v = stage[bs + i];
        buf[i] = v;
        atomicAdd(&cnt[v >> 17], 1);
    }
    __syncthreads();
    const int c = cnt[t];
    scn[t] = c;
    __syncthreads();
    for (int off = 1; off < BKT; off <<= 1) {
        int u = (t >= off) ? scn[t - off] : 0;
        __syncthreads();
        scn[t] += u;
        __syncthreads();
    }
    const int excl = scn[t] - c;
    cur[t] = excl;
    const float d = rsqrtf((float)c + 1.0f);
    dv[t] = d;
    const int node = b * BKT + t;
    if (node < N) {
        row[node] = bs + excl;
        dinv[node] = d;
    }
    __syncthreads();
    for (int i = t; i < m; i += THREADS) {
        const unsigned v = buf[i];
        const int pos = atomicAdd(&cur[v >> 17], 1);
        stage[bs + pos] = v & 0x1FFFFu;
    }
    // Rescale this bucket's H1 rows by dinv (deferred layer-1 scaling).
    const unsigned node0 = (unsigned)b * BKT;
    const int nn = min(BKT, N - (int)node0);
    unsigned* Hrow = H2 + node0 * 32u;
    for (int i = t; i < nn * 32; i += THREADS) {
        const float di = dv[i >> 5];
        const unsigned v = Hrow[i];
        const float lo = bflo(v) * di;
        const float hi = bfhi(v) * di;
        Hrow[i] = ((unsigned)f2bf(hi) << 16) | (unsigned)f2bf(lo);
    }
}

// ---- Aggregation: wave per node, pair-gather, 32-bit indices, bf16 out -----

__global__ __launch_bounds__(THREADS) void agg_kernel(const unsigned* __restrict__ srt,
                                                      const int* __restrict__ row,
                                                      const float* __restrict__ dinv,
                                                      const unsigned* __restrict__ H2,  // [N][32] bf16 pairs
                                                      const float* __restrict__ bias,
                                                      unsigned* __restrict__ out2,      // [N][32] bf16 pairs
                                                      int N, int E) {
    const int idx = blockIdx.x * blockDim.x + threadIdx.x;
    const int node = idx >> 6;
    if (node >= N) return;
    const int l = threadIdx.x & 63;
    const unsigned half = (unsigned)(l >> 5);
    const unsigned f2 = (unsigned)(l & 31);
    const int start = row[node];
    const int end = (node + 1 < N) ? row[node + 1] : E;
    float acc0 = 0.0f, acc1 = 0.0f;

    int base = start;
    for (; base + 16 <= end; base += 16) {
        const unsigned* sp = srt + __builtin_amdgcn_readfirstlane(base);
        const unsigned g0 = sp[0],  g1 = sp[1],  g2 = sp[2],  g3 = sp[3];
        const unsigned g4 = sp[4],  g5 = sp[5],  g6 = sp[6],  g7 = sp[7];
        const unsigned h0 = sp[8],  h1 = sp[9],  h2 = sp[10], h3 = sp[11];
        const unsigned h4 = sp[12], h5 = sp[13], h6 = sp[14], h7 = sp[15];
        // 32-bit dword indices (max (2^17-1)*32+31 < 2^31): saddr+voffset form.
        const unsigned i0 = ((half ? h0 : g0) << 5) + f2;
        const unsigned i1 = ((half ? h1 : g1) << 5) + f2;
        const unsigned i2 = ((half ? h2 : g2) << 5) + f2;
        const unsigned i3 = ((half ? h3 : g3) << 5) + f2;
        const unsigned i4 = ((half ? h4 : g4) << 5) + f2;
        const unsigned i5 = ((half ? h5 : g5) << 5) + f2;
        const unsigned i6 = ((half ? h6 : g6) << 5) + f2;
        const unsigned i7 = ((half ? h7 : g7) << 5) + f2;
        const unsigned v0 = H2[i0];
        const unsigned v1 = H2[i1];
        const unsigned v2 = H2[i2];
        const unsigned v3 = H2[i3];
        const unsigned v4 = H2[i4];
        const unsigned v5 = H2[i5];
        const unsigned v6 = H2[i6];
        const unsigned v7 = H2[i7];
        acc0 += bflo(v0); acc1 += bfhi(v0);
        acc0 += bflo(v1); acc1 += bfhi(v1);
        acc0 += bflo(v2); acc1 += bfhi(v2);
        acc0 += bflo(v3); acc1 += bfhi(v3);
        acc0 += bflo(v4); acc1 += bfhi(v4);
        acc0 += bflo(v5); acc1 += bfhi(v5);
        acc0 += bflo(v6); acc1 += bfhi(v6);
        acc0 += bflo(v7); acc1 += bfhi(v7);
    }
    if (base < end) {
        const unsigned* sp = srt + __builtin_amdgcn_readfirstlane(base);
        const unsigned cap = (unsigned)(N - 1);
        const int j0 = base + (int)half * 8;
#pragma unroll
        for (int k = 0; k < 8; ++k) {
            const unsigned raw = half ? sp[8 + k] : sp[k];   // may read past end: in-ws, safe
            const bool ok = (j0 + k) < end;
            const unsigned s = min(raw & 0x1FFFFu, cap);
            const unsigned v = H2[(s << 5) + f2];
            acc0 += ok ? bflo(v) : 0.0f;
            acc1 += ok ? bfhi(v) : 0.0f;
        }
    }

    acc0 += __shfl_xor(acc0, 32, 64);
    acc1 += __shfl_xor(acc1, 32, 64);
    if (half == 0) {
        const unsigned ni = ((unsigned)node << 5) + f2;
        const unsigned sv = H2[ni];                      // self-loop row (already *dinv)
        const float d = dinv[node];
        const float2 b = *(const float2*)(bias + f2 * 2);
        const float o0 = fmaxf(fmaf(acc0 + bflo(sv), d, b.x), 0.0f);
        const float o1 = fmaxf(fmaf(acc1 + bfhi(sv), d, b.y), 0.0f);
        out2[ni] = ((unsigned)f2bf(o1) << 16) | (unsigned)f2bf(o0);
    }
}

// ---- Launch ----------------------------------------------------------------

extern "C" void kernel_launch(void* const* d_in, const int* in_sizes, int n_in,
                              void* d_out, int out_size, void* d_ws, size_t ws_size,
                              hipStream_t stream) {
    const float* x   = (const float*)d_in[0];
    const int*   ei  = (const int*)d_in[1];   // [2, E] int32
    const float* W1  = (const float*)d_in[3];
    const float* b1  = (const float*)d_in[4];
    const float* W2  = (const float*)d_in[5];
    const float* b2  = (const float*)d_in[6];
    const float* Wfc = (const float*)d_in[7];
    const float* bfc = (const float*)d_in[8];
    float* out = (float*)d_out;

    const int N = in_sizes[0] / 128;
    const int E = in_sizes[1] / 2;
    const int* src = ei;
    const int* dst = ei + E;

    const int nb   = (N + BKT - 1) / BKT;     // 391 buckets
    const int nblk = (E + EPB - 1) / EPB;     // 391 edge-chunks

    // Workspace (256 B-aligned slices).
    char* p = (char*)d_ws;
    auto alloc = [&](size_t bytes) { char* r = p; p += (bytes + 255) & ~(size_t)255; return r; };
    int*      bh     = (int*)alloc((size_t)nb * nblk * 4);
    int*      btot   = (int*)alloc((size_t)nb * 4);
    int*      bstart = (int*)alloc((size_t)(nb + 1) * 4);
    unsigned* stage  = (unsigned*)alloc((size_t)E * 4);
    int*      row    = (int*)alloc((size_t)N * 4);
    float*    dinv   = (float*)alloc((size_t)N * 4);
    ushort_t* bufH   = (ushort_t*)alloc((size_t)N * 64 * 2);   // H tables (bf16)
    ushort_t* bufR   = (ushort_t*)alloc((size_t)N * 64 * 2);   // relu outputs (bf16)

    const int gW  = ((N * 64) + THREADS - 1) / THREADS;  // one wave per node
    const int mmB = (N + 63) / 64;

    // 1) Fused: hist (nblk blocks) + mm1 MFMA (fp32 in, unscaled bf16 out).
    mm_mfma_kernel<128, 64, 0, true><<<nblk + mmB, THREADS, 0, stream>>>(
        x, nullptr, W1, nullptr, nullptr, bufH, N, dst, E, nb, nblk, bh);
    // 2-4) partition -> sorted CSR; sortB rescales H1 by dinv.
    scanS_kernel<<<nb, THREADS, 0, stream>>>(bh, nb, nblk, btot);
    binB_kernel<<<nblk, BIN_T, 0, stream>>>(src, dst, E, nb, nblk, bh, btot, bstart, stage);
    sortB_kernel<<<nb, THREADS, 0, stream>>>(stage, bstart, nb, N, row, dinv, (unsigned*)bufH);
    // 5) layer-1 aggregate -> relu1 bf16.
    agg_kernel<<<gW, THREADS, 0, stream>>>(stage, row, dinv, (const unsigned*)bufH, b1,
                                           (unsigned*)bufR, N, E);
    // 6) mm2 (MFMA, bf16 in, *dinv bf16 out).
    mm_mfma_kernel<64, 64, 1, false><<<mmB, THREADS, 0, stream>>>(
        nullptr, bufR, W2, dinv, nullptr, bufH, N, nullptr, 0, 0, 0, nullptr);
    // 7) layer-2 aggregate -> relu2 bf16.
    agg_kernel<<<gW, THREADS, 0, stream>>>(stage, row, dinv, (const unsigned*)bufH, b2,
                                           (unsigned*)bufR, N, E);
    // 8) FC (MFMA, bf16 in, f32 out + bias).
    mm_mfma_kernel<64, 32, 2, false><<<mmB, THREADS, 0, stream>>>(
        nullptr, bufR, Wfc, nullptr, bfc, out, N, nullptr, 0, 0, 0, nullptr);
}

// Round 15
// 244.748 us; speedup vs baseline: 2.3846x; 1.0333x over previous
//
#include <hip/hip_runtime.h>

// GCN: 2x (GCNConv + ReLU) + FC.  N=100000, E=1600000, F: 128 -> 64 -> 64 -> 32. fp32.
//
// R15: mm2 and fc are ROW-LOCAL (Y[i] = f(relu[i])) -> fused into the agg
// kernels.  aggmm block owns 64 nodes (4 waves x 16 nodes); relu goes into a
// 64x64 bf16 LDS tile (MFMA-A layout, 72-ushort padded stride), then the block
// runs the K=64 MFMA vs LDS-staged W^T and writes the next table directly.
// Removes mm2+fc dispatches and both relu global round-trips. 6 dispatches:
// mm1+hist -> scanS -> binB -> sortB(+H1 rescale) -> aggmm(M=64,*dinv,bf16)
// -> aggmm(M=32,+bias,f32).  Partition (R6/R12), gather core (R10/R14),
// MFMA tile (R13/R14) unchanged.

#define THREADS 256
#define BIN_T 512
#define EPB 4096
#define BKT 256
#define SORT_CAP 8192

typedef unsigned short ushort_t;
typedef __attribute__((ext_vector_type(8))) short short8;
typedef __attribute__((ext_vector_type(4))) float f32x4;

__device__ __forceinline__ ushort_t f2bf(float f) {  // round-to-nearest-even
    unsigned u = __float_as_uint(f);
    u += 0x7FFFu + ((u >> 16) & 1u);
    return (ushort_t)(u >> 16);
}
__device__ __forceinline__ float bflo(unsigned v) { return __uint_as_float(v << 16); }
__device__ __forceinline__ float bfhi(unsigned v) { return __uint_as_float(v & 0xFFFF0000u); }

// ---- Kernel 1: MFMA mm1 (fp32 in, unscaled bf16 out) + fused histogram -----

template <int K, int M>
__global__ __launch_bounds__(THREADS) void mm1h_kernel(const float* __restrict__ Xf,
                                                       const float* __restrict__ W,
                                                       ushort_t* __restrict__ Yv, int N,
                                                       const int* __restrict__ dst, int E,
                                                       int nb, int nblk,
                                                       int* __restrict__ bh) {
    constexpr int XROW = K + 4;
    constexpr int XB = 64 * XROW * 4;
    constexpr int WROW = K + 8;
    constexpr int WB = M * WROW * 2;
    constexpr int CB = 64 * M * 4;
    constexpr int SMEM = (XB + WB > CB) ? (XB + WB) : CB;
    __shared__ __align__(16) char smem[SMEM];
    const int t = threadIdx.x;

    if ((int)blockIdx.x < nblk) {
        int* h = (int*)smem;
        for (int i = t; i < nb; i += THREADS) h[i] = 0;
        __syncthreads();
        const int e0 = blockIdx.x * EPB;
        const int e1 = min(e0 + EPB, E);
        for (int e = e0 + t; e < e1; e += THREADS)
            atomicAdd(&h[dst[e] >> 8], 1);
        __syncthreads();
        for (int i = t; i < nb; i += THREADS)
            bh[(size_t)i * nblk + blockIdx.x] = h[i];
        return;
    }
    const int row0 = ((int)blockIdx.x - nblk) * 64;

    ushort_t* WsU = (ushort_t*)(smem + XB);
    for (int i = t; i < K * M; i += THREADS) {
        const int k = i / M, m = i % M;
        WsU[m * WROW + k] = f2bf(W[i]);
    }
    float* XsF = (float*)smem;
    for (int i = t; i < 64 * K / 4; i += THREADS) {
        const int r = i / (K / 4), kc = i % (K / 4);
        const unsigned gr = (unsigned)min(row0 + r, N - 1);
        *(float4*)(XsF + r * XROW + kc * 4) = *(const float4*)(Xf + (size_t)gr * K + kc * 4);
    }
    __syncthreads();

    const int w = t >> 6, lane = t & 63;
    const int m0 = w * 16, lm = lane & 15, q = lane >> 4;
    f32x4 acc[M / 16];
#pragma unroll
    for (int c = 0; c < M / 16; ++c) acc[c] = (f32x4)0.0f;

#pragma unroll
    for (int s = 0; s < K / 32; ++s) {
        const float* xr = (const float*)smem + (size_t)(m0 + lm) * XROW + s * 32 + q * 8;
        const float4 f0 = *(const float4*)xr;
        const float4 f1 = *(const float4*)(xr + 4);
        short8 a;
        a[0] = (short)f2bf(f0.x); a[1] = (short)f2bf(f0.y);
        a[2] = (short)f2bf(f0.z); a[3] = (short)f2bf(f0.w);
        a[4] = (short)f2bf(f1.x); a[5] = (short)f2bf(f1.y);
        a[6] = (short)f2bf(f1.z); a[7] = (short)f2bf(f1.w);
#pragma unroll
        for (int c = 0; c < M / 16; ++c) {
            const short8 b = *(const short8*)(WsU + (size_t)(c * 16 + lm) * WROW + s * 32 + q * 8);
            acc[c] = __builtin_amdgcn_mfma_f32_16x16x32_bf16(a, b, acc[c], 0, 0, 0);
        }
    }
    __syncthreads();
    float* Cs = (float*)smem;
#pragma unroll
    for (int c = 0; c < M / 16; ++c)
#pragma unroll
        for (int r = 0; r < 4; ++r)
            Cs[(size_t)(m0 + q * 4 + r) * M + c * 16 + lm] = acc[c][r];
    __syncthreads();

    for (int g = t; g < 64 * M / 4; g += THREADS) {
        const int r = g / (M / 4);
        const int gr = row0 + r;
        if (gr >= N) continue;
        const float4 o = *(const float4*)(Cs + (size_t)g * 4);
        const int col = (g % (M / 4)) * 4;
        ushort4 pk = {f2bf(o.x), f2bf(o.y), f2bf(o.z), f2bf(o.w)};
        *(ushort4*)(Yv + (size_t)gr * M + col) = pk;
    }
}

// ---- Pass 2: per-bucket row scan ------------------------------------------

__global__ __launch_bounds__(THREADS) void scanS_kernel(int* __restrict__ bh,
                                                        int nb, int nblk,
                                                        int* __restrict__ btot) {
    __shared__ int s[THREADS];
    const int b = blockIdx.x, t = threadIdx.x;
    int* rowp = bh + (size_t)b * nblk;
    const int run = (nblk + THREADS - 1) / THREADS;
    const int lo = min(t * run, nblk), hi = min(lo + run, nblk);
    int v[4];
    int sum = 0;
    for (int i = lo; i < hi; ++i) { v[i - lo] = rowp[i]; sum += v[i - lo]; }
    s[t] = sum;
    __syncthreads();
    for (int off = 1; off < THREADS; off <<= 1) {
        int u = (t >= off) ? s[t - off] : 0;
        __syncthreads();
        s[t] += u;
        __syncthreads();
    }
    int pre = s[t] - sum;
    for (int i = lo; i < hi; ++i) { rowp[i] = pre; pre += v[i - lo]; }
    if (t == THREADS - 1) btot[b] = s[t];
}

// ---- Pass 3: bin edges (inline bucket-total scan) --------------------------

__global__ __launch_bounds__(BIN_T) void binB_kernel(const int* __restrict__ src,
                                                     const int* __restrict__ dst, int E,
                                                     int nb, int nblk,
                                                     const int* __restrict__ bh,
                                                     const int* __restrict__ btot,
                                                     int* __restrict__ bstart,
                                                     unsigned* __restrict__ stage) {
    __shared__ int s[BIN_T];
    __shared__ int cur[BIN_T];
    const int t = threadIdx.x;
    const int v = (t < nb) ? btot[t] : 0;
    s[t] = v;
    __syncthreads();
    for (int off = 1; off < BIN_T; off <<= 1) {
        int u = (t >= off) ? s[t - off] : 0;
        __syncthreads();
        s[t] += u;
        __syncthreads();
    }
    const int base = s[t] - v;
    if (t < nb) cur[t] = base + bh[(size_t)t * nblk + blockIdx.x];
    if (blockIdx.x == 0) {
        if (t < nb) bstart[t] = base;
        if (t == 0) bstart[nb] = E;
    }
    __syncthreads();
    const int e0 = blockIdx.x * EPB;
    const int e1 = min(e0 + EPB, E);
    for (int e = e0 + t; e < e1; e += BIN_T) {
        const int d = dst[e];
        const int pos = atomicAdd(&cur[d >> 8], 1);
        stage[pos] = ((unsigned)(d & (BKT - 1)) << 17) | (unsigned)src[e];
    }
}

// ---- Pass 4: per-bucket counting sort + row/dinv + H1 rescale --------------

__global__ __launch_bounds__(THREADS) void sortB_kernel(unsigned* __restrict__ stage,
                                                        const int* __restrict__ bstart,
                                                        int nb, int N,
                                                        int* __restrict__ row,
                                                        float* __restrict__ dinv,
                                                        unsigned* __restrict__ H2) {
    __shared__ unsigned buf[SORT_CAP];
    __shared__ int cnt[BKT], cur[BKT], scn[BKT];
    __shared__ float dv[BKT];
    const int b = blockIdx.x, t = threadIdx.x;
    const int bs = bstart[b];
    const int be = bstart[b + 1];
    const int m = be - bs;
    cnt[t] = 0;
    __syncthreads();
    for (int i = t; i < m; i += THREADS) {
        const unsigned v = stage[bs + i];
        buf[i] = v;
        atomicAdd(&cnt[v >> 17], 1);
    }
    __syncthreads();
    const int c = cnt[t];
    scn[t] = c;
    __syncthreads();
    for (int off = 1; off < BKT; off <<= 1) {
        int u = (t >= off) ? scn[t - off] : 0;
        __syncthreads();
        scn[t] += u;
        __syncthreads();
    }
    const int excl = scn[t] - c;
    cur[t] = excl;
    const float d = rsqrtf((float)c + 1.0f);
    dv[t] = d;
    const int node = b * BKT + t;
    if (node < N) {
        row[node] = bs + excl;
        dinv[node] = d;
    }
    __syncthreads();
    for (int i = t; i < m; i += THREADS) {
        const unsigned v = buf[i];
        const int pos = atomicAdd(&cur[v >> 17], 1);
        stage[bs + pos] = v & 0x1FFFFu;
    }
    const unsigned node0 = (unsigned)b * BKT;
    const int nn = min(BKT, N - (int)node0);
    unsigned* Hrow = H2 + node0 * 32u;
    for (int i = t; i < nn * 32; i += THREADS) {
        const float di = dv[i >> 5];
        const unsigned v = Hrow[i];
        const float lo = bflo(v) * di;
        const float hi = bfhi(v) * di;
        Hrow[i] = ((unsigned)f2bf(hi) << 16) | (unsigned)f2bf(lo);
    }
}

// ---- Fused aggregate + row-local MFMA matmul -------------------------------
// Block owns 64 nodes; wave w handles nodes w*16..w*16+15 sequentially.
// Phase 1 (gather): relu(dinv*(Hself+sum)+abias) -> bf16 LDS tile Rl[64][72u].
// Phase 2 (MFMA):  Y[64][M] = Rl @ W (W fp32 [64][M] staged transposed bf16).
// MODE 1: Y *= dinv -> bf16 pair table.  MODE 2: Y += fbias -> fp32 out.

template <int M, int MODE>
__global__ __launch_bounds__(THREADS) void aggmm_kernel(const unsigned* __restrict__ srt,
                                                        const int* __restrict__ row,
                                                        const float* __restrict__ dinv,
                                                        const unsigned* __restrict__ H2,
                                                        const float* __restrict__ abias,
                                                        const float* __restrict__ W,
                                                        const float* __restrict__ fbias,
                                                        void* __restrict__ Yv,
                                                        int N, int E) {
    constexpr int K = 64;
    constexpr int RROW = 36;                 // relu-tile row stride in dwords (72 ushorts)
    constexpr int RB = 64 * RROW * 4;        // 9216 B
    constexpr int WROW = K + 8;              // 72 ushorts
    constexpr int WB = M * WROW * 2;
    constexpr int CB = 64 * M * 4;
    constexpr int SMEM = (RB + WB > CB) ? (RB + WB) : CB;
    __shared__ __align__(16) char smem[SMEM];
    const int t = threadIdx.x;
    const int w = t >> 6, lane = t & 63;
    const int row0 = blockIdx.x * 64;

    // Stage W^T bf16 (phase 1 doesn't read it; barrier below covers it).
    ushort_t* WsU = (ushort_t*)(smem + RB);
    for (int i = t; i < K * M; i += THREADS) {
        const int k = i / M, m = i % M;
        WsU[m * WROW + k] = f2bf(W[i]);
    }

    // Phase 1: gather+relu for this wave's 16 nodes.
    unsigned* Rl = (unsigned*)smem;
    const unsigned half = (unsigned)(lane >> 5);
    const unsigned f2 = (unsigned)(lane & 31);
#pragma unroll 1
    for (int i = 0; i < 16; ++i) {
        const int node = row0 + w * 16 + i;
        if (node >= N) break;
        const int start = row[node];
        const int end = (node + 1 < N) ? row[node + 1] : E;
        float acc0 = 0.0f, acc1 = 0.0f;
        int base = start;
        for (; base + 16 <= end; base += 16) {
            const unsigned* sp = srt + __builtin_amdgcn_readfirstlane(base);
            const unsigned g0 = sp[0],  g1 = sp[1],  g2 = sp[2],  g3 = sp[3];
            const unsigned g4 = sp[4],  g5 = sp[5],  g6 = sp[6],  g7 = sp[7];
            const unsigned h0 = sp[8],  h1 = sp[9],  h2 = sp[10], h3 = sp[11];
            const unsigned h4 = sp[12], h5 = sp[13], h6 = sp[14], h7 = sp[15];
            const unsigned i0 = ((half ? h0 : g0) << 5) + f2;
            const unsigned i1 = ((half ? h1 : g1) << 5) + f2;
            const unsigned i2 = ((half ? h2 : g2) << 5) + f2;
            const unsigned i3 = ((half ? h3 : g3) << 5) + f2;
            const unsigned i4 = ((half ? h4 : g4) << 5) + f2;
            const unsigned i5 = ((half ? h5 : g5) << 5) + f2;
            const unsigned i6 = ((half ? h6 : g6) << 5) + f2;
            const unsigned i7 = ((half ? h7 : g7) << 5) + f2;
            const unsigned v0 = H2[i0];
            const unsigned v1 = H2[i1];
            const unsigned v2 = H2[i2];
            const unsigned v3 = H2[i3];
            const unsigned v4 = H2[i4];
            const unsigned v5 = H2[i5];
            const unsigned v6 = H2[i6];
            const unsigned v7 = H2[i7];
            acc0 += bflo(v0); acc1 += bfhi(v0);
            acc0 += bflo(v1); acc1 += bfhi(v1);
            acc0 += bflo(v2); acc1 += bfhi(v2);
            acc0 += bflo(v3); acc1 += bfhi(v3);
            acc0 += bflo(v4); acc1 += bfhi(v4);
            acc0 += bflo(v5); acc1 += bfhi(v5);
            acc0 += bflo(v6); acc1 += bfhi(v6);
            acc0 += bflo(v7); acc1 += bfhi(v7);
        }
        if (base < end) {
            const unsigned* sp = srt + __builtin_amdgcn_readfirstlane(base);
            const unsigned cap = (unsigned)(N - 1);
            const int j0 = base + (int)half * 8;
#pragma unroll
            for (int k = 0; k < 8; ++k) {
                const unsigned raw = half ? sp[8 + k] : sp[k];   // past-end reads stay in ws
                const bool ok = (j0 + k) < end;
                const unsigned s = min(raw & 0x1FFFFu, cap);
                const unsigned v = H2[(s << 5) + f2];
                acc0 += ok ? bflo(v) : 0.0f;
                acc1 += ok ? bfhi(v) : 0.0f;
            }
        }
        acc0 += __shfl_xor(acc0, 32, 64);
        acc1 += __shfl_xor(acc1, 32, 64);
        if (half == 0) {
            const unsigned sv = H2[((unsigned)node << 5) + f2];  // self-loop (already *dinv)
            const float d = dinv[node];
            const float2 b = *(const float2*)(abias + f2 * 2);
            const float o0 = fmaxf(fmaf(acc0 + bflo(sv), d, b.x), 0.0f);
            const float o1 = fmaxf(fmaf(acc1 + bfhi(sv), d, b.y), 0.0f);
            Rl[(w * 16 + i) * RROW + f2] = ((unsigned)f2bf(o1) << 16) | (unsigned)f2bf(o0);
        }
    }
    __syncthreads();

    // Phase 2: MFMA over the relu tile.
    const int m0 = w * 16, lm = lane & 15, q = lane >> 4;
    f32x4 acc[M / 16];
#pragma unroll
    for (int c = 0; c < M / 16; ++c) acc[c] = (f32x4)0.0f;
#pragma unroll
    for (int s = 0; s < K / 32; ++s) {
        const short8 a = *(const short8*)((const ushort_t*)Rl + (size_t)(m0 + lm) * 72 + s * 32 + q * 8);
#pragma unroll
        for (int c = 0; c < M / 16; ++c) {
            const short8 b = *(const short8*)(WsU + (size_t)(c * 16 + lm) * WROW + s * 32 + q * 8);
            acc[c] = __builtin_amdgcn_mfma_f32_16x16x32_bf16(a, b, acc[c], 0, 0, 0);
        }
    }
    __syncthreads();   // Rl/Ws dead; reuse as C [64][M] f32
    float* Cs = (float*)smem;
#pragma unroll
    for (int c = 0; c < M / 16; ++c)
#pragma unroll
        for (int r = 0; r < 4; ++r)
            Cs[(size_t)(m0 + q * 4 + r) * M + c * 16 + lm] = acc[c][r];
    __syncthreads();

    for (int g = t; g < 64 * M / 4; g += THREADS) {
        const int r = g / (M / 4);
        const int gr = row0 + r;
        if (gr >= N) continue;
        float4 o = *(const float4*)(Cs + (size_t)g * 4);
        const int col = (g % (M / 4)) * 4;
        if (MODE == 1) {
            const float d = dinv[gr];
            o.x *= d; o.y *= d; o.z *= d; o.w *= d;
            ushort4 pk = {f2bf(o.x), f2bf(o.y), f2bf(o.z), f2bf(o.w)};
            *(ushort4*)((ushort_t*)Yv + (size_t)gr * M + col) = pk;
        } else {
            o.x += fbias[col]; o.y += fbias[col + 1];
            o.z += fbias[col + 2]; o.w += fbias[col + 3];
            *(float4*)((float*)Yv + (size_t)gr * M + col) = o;
        }
    }
}

// ---- Launch ----------------------------------------------------------------

extern "C" void kernel_launch(void* const* d_in, const int* in_sizes, int n_in,
                              void* d_out, int out_size, void* d_ws, size_t ws_size,
                              hipStream_t stream) {
    const float* x   = (const float*)d_in[0];
    const int*   ei  = (const int*)d_in[1];   // [2, E] int32
    const float* W1  = (const float*)d_in[3];
    const float* b1  = (const float*)d_in[4];
    const float* W2  = (const float*)d_in[5];
    const float* b2  = (const float*)d_in[6];
    const float* Wfc = (const float*)d_in[7];
    const float* bfc = (const float*)d_in[8];
    float* out = (float*)d_out;

    const int N = in_sizes[0] / 128;
    const int E = in_sizes[1] / 2;
    const int* src = ei;
    const int* dst = ei + E;

    const int nb   = (N + BKT - 1) / BKT;     // 391 buckets
    const int nblk = (E + EPB - 1) / EPB;     // 391 edge-chunks

    // Workspace (256 B-aligned slices).
    char* p = (char*)d_ws;
    auto alloc = [&](size_t bytes) { char* r = p; p += (bytes + 255) & ~(size_t)255; return r; };
    int*      bh     = (int*)alloc((size_t)nb * nblk * 4);
    int*      btot   = (int*)alloc((size_t)nb * 4);
    int*      bstart = (int*)alloc((size_t)(nb + 1) * 4);
    unsigned* stage  = (unsigned*)alloc((size_t)E * 4);
    int*      row    = (int*)alloc((size_t)N * 4);     // also absorbs agg tail over-reads
    float*    dinv   = (float*)alloc((size_t)N * 4);
    ushort_t* bufH   = (ushort_t*)alloc((size_t)N * 64 * 2);   // H1 table (bf16)
    ushort_t* bufR   = (ushort_t*)alloc((size_t)N * 64 * 2);   // H2 table (bf16)

    const int mmB = (N + 63) / 64;

    // 1) Fused: hist (nblk blocks) + mm1 MFMA (fp32 in, unscaled bf16 out).
    mm1h_kernel<128, 64><<<nblk + mmB, THREADS, 0, stream>>>(
        x, W1, bufH, N, dst, E, nb, nblk, bh);
    // 2-4) partition -> sorted CSR; sortB rescales H1 by dinv.
    scanS_kernel<<<nb, THREADS, 0, stream>>>(bh, nb, nblk, btot);
    binB_kernel<<<nblk, BIN_T, 0, stream>>>(src, dst, E, nb, nblk, bh, btot, bstart, stage);
    sortB_kernel<<<nb, THREADS, 0, stream>>>(stage, bstart, nb, N, row, dinv, (unsigned*)bufH);
    // 5) agg layer1 + mm2 fused -> H2 table (bf16, *dinv).
    aggmm_kernel<64, 1><<<mmB, THREADS, 0, stream>>>(
        stage, row, dinv, (const unsigned*)bufH, b1, W2, nullptr, bufR, N, E);
    // 6) agg layer2 + fc fused -> fp32 out (+bfc).
    aggmm_kernel<32, 2><<<mmB, THREADS, 0, stream>>>(
        stage, row, dinv, (const unsigned*)bufR, b2, Wfc, bfc, out, N, E);
}